// Round 1
// baseline (2097.506 us; speedup 1.0000x reference)
//
#include <hip/hip_runtime.h>
#include <cstdint>
#include <cstddef>

#define BATCH 16384
#define NPERM 20
#define NOBJ 5

typedef unsigned short u16;
typedef unsigned int u32;

__device__ __forceinline__ u16 bf16_rne(float x) {
    u32 u = __float_as_uint(x);
    u += 0x7fffu + ((u >> 16) & 1u);
    return (u16)(u >> 16);
}
__device__ __forceinline__ float blo(u32 u) { return __uint_as_float(u << 16); }
__device__ __forceinline__ float bhi(u32 u) { return __uint_as_float(u & 0xffff0000u); }

// ---------------- transpose rho_W1 (128x256 -> 256x128) ----------------
__global__ __launch_bounds__(256) void kT(const float* __restrict__ rho,
                                          float* __restrict__ rhoT) {
    int t = blockIdx.x * 256 + threadIdx.x;   // 32768 total
    int j = t >> 7;          // 0..255
    int k = t & 127;         // 0..127
    rhoT[j * 128 + k] = rho[k * 256 + j];
}

// ---------------- Stage A: edge MLP rows (b,perm) ----------------
// inp(8) -> h(256) relu -> mp_out(128) relu ; score = mp_out . eaW + eab
// writes mp_out rows as bf16, score as f32
__global__ __launch_bounds__(256) void kA(
    const float* __restrict__ obs, const float* __restrict__ ag, const float* __restrict__ g,
    const float* __restrict__ W1, const float* __restrict__ b1,
    const float* __restrict__ W2, const float* __restrict__ b2,
    const float* __restrict__ eaW, const float* __restrict__ eab,
    const int* __restrict__ src, const int* __restrict__ dst, const int* __restrict__ pred,
    u16* __restrict__ mp_ws, float* __restrict__ e_ws)
{
    const int row = blockIdx.x * 256 + threadIdx.x;   // 0..327679
    const int b = row / NPERM;
    const int p = row - b * NPERM;

    float inp[8];
    {
        const int i0 = pred[2 * p + 0];
        const int i1 = pred[2 * p + 1];
        const float* gb = g + (size_t)b * (2 * NPERM);
        const float* ab = ag + (size_t)b * (2 * NPERM);
        inp[0] = gb[i0] - ab[i0];
        inp[1] = gb[i1] - ab[i1];
        const int so = src[p];
        const int dd = dst[p];
        const float* ob = obs + (size_t)b * 85 + 10;
        inp[2] = ob[so * 15 + 0];
        inp[3] = ob[so * 15 + 1];
        inp[4] = ob[so * 15 + 2];
        inp[5] = ob[dd * 15 + 0];
        inp[6] = ob[dd * 15 + 1];
        inp[7] = ob[dd * 15 + 2];
    }

    float score = eab[0];

    #pragma unroll 1
    for (int half = 0; half < 2; ++half) {
        float acc[64];
        #pragma unroll
        for (int c = 0; c < 64; ++c) acc[c] = b2[half * 64 + c];

        #pragma unroll 1
        for (int kc = 0; kc < 8; ++kc) {    // 8 chunks of 32 over K=256
            float h[32];
            #pragma unroll
            for (int j = 0; j < 32; ++j) {
                float t = b1[kc * 32 + j];
                #pragma unroll
                for (int i = 0; i < 8; ++i)
                    t = fmaf(inp[i], W1[i * 256 + kc * 32 + j], t);
                h[j] = fmaxf(t, 0.0f);
            }
            #pragma unroll
            for (int j = 0; j < 32; ++j) {
                const float hv = h[j];
                const float* w = W2 + (kc * 32 + j) * 128 + half * 64;
                #pragma unroll
                for (int c = 0; c < 64; ++c)
                    acc[c] = fmaf(hv, w[c], acc[c]);
            }
        }

        #pragma unroll
        for (int c = 0; c < 64; ++c) {
            acc[c] = fmaxf(acc[c], 0.0f);
            score = fmaf(acc[c], eaW[half * 64 + c], score);
        }

        u16* mrow = mp_ws + (size_t)row * 128 + half * 64;
        #pragma unroll
        for (int cc = 0; cc < 64; cc += 8) {
            uint4 v;
            v.x = (u32)bf16_rne(acc[cc + 0]) | ((u32)bf16_rne(acc[cc + 1]) << 16);
            v.y = (u32)bf16_rne(acc[cc + 2]) | ((u32)bf16_rne(acc[cc + 3]) << 16);
            v.z = (u32)bf16_rne(acc[cc + 4]) | ((u32)bf16_rne(acc[cc + 5]) << 16);
            v.w = (u32)bf16_rne(acc[cc + 6]) | ((u32)bf16_rne(acc[cc + 7]) << 16);
            *reinterpret_cast<uint4*>(mrow + cc) = v;
        }
    }
    e_ws[row] = score;
}

// ---------------- Stage B: per-(b,obj) softmax over 4 incoming edges + weighted sum ----------------
__global__ __launch_bounds__(256) void kB(
    const u16* __restrict__ mp_ws, const float* __restrict__ e_ws,
    const int* __restrict__ inc, float* __restrict__ edge_ws)
{
    const int t = blockIdx.x * 256 + threadIdx.x;  // 0..81919
    const int b = t / NOBJ;
    const int o = t - b * NOBJ;

    int r[4];
    float sc[4];
    #pragma unroll
    for (int i = 0; i < 4; ++i) {
        r[i] = b * NPERM + inc[o * 4 + i];
        sc[i] = e_ws[r[i]];
    }
    float m = fmaxf(fmaxf(sc[0], sc[1]), fmaxf(sc[2], sc[3]));
    float w[4];
    float den = 0.0f;
    #pragma unroll
    for (int i = 0; i < 4; ++i) { w[i] = expf(sc[i] - m); den += w[i]; }
    const float inv = 1.0f / den;
    #pragma unroll
    for (int i = 0; i < 4; ++i) w[i] *= inv;

    float* outp = edge_ws + (size_t)t * 128;
    #pragma unroll 1
    for (int cc = 0; cc < 128; cc += 8) {
        float acc[8] = {0, 0, 0, 0, 0, 0, 0, 0};
        #pragma unroll
        for (int i = 0; i < 4; ++i) {
            const uint4 v = *reinterpret_cast<const uint4*>(mp_ws + (size_t)r[i] * 128 + cc);
            const float wi = w[i];
            acc[0] = fmaf(wi, blo(v.x), acc[0]);
            acc[1] = fmaf(wi, bhi(v.x), acc[1]);
            acc[2] = fmaf(wi, blo(v.y), acc[2]);
            acc[3] = fmaf(wi, bhi(v.y), acc[3]);
            acc[4] = fmaf(wi, blo(v.z), acc[4]);
            acc[5] = fmaf(wi, bhi(v.z), acc[5]);
            acc[6] = fmaf(wi, blo(v.w), acc[6]);
            acc[7] = fmaf(wi, bhi(v.w), acc[7]);
        }
        float4 f0 = make_float4(acc[0], acc[1], acc[2], acc[3]);
        float4 f1 = make_float4(acc[4], acc[5], acc[6], acc[7]);
        *reinterpret_cast<float4*>(outp + cc + 0) = f0;
        *reinterpret_cast<float4*>(outp + cc + 4) = f1;
    }
}

// ---------------- Stage C: node MLP rows (b,obj) ----------------
// inp(153) = [body(10), obj(15), edge_feat(128)] -> ph(256) relu -> phi_out(128) relu
// score = phi_out . saW + sab
__global__ __launch_bounds__(256) void kC(
    const float* __restrict__ obs, const float* __restrict__ edge_ws,
    const float* __restrict__ W1, const float* __restrict__ b1,
    const float* __restrict__ W2, const float* __restrict__ b2,
    const float* __restrict__ saW, const float* __restrict__ sab,
    float* __restrict__ phi_ws, float* __restrict__ s_ws)
{
    const int t = blockIdx.x * 256 + threadIdx.x;  // 0..81919
    const int b = t / NOBJ;
    const int o = t - b * NOBJ;

    const float* body = obs + (size_t)b * 85;
    const float* objp = body + 10 + o * 15;
    const float* ef = edge_ws + (size_t)t * 128;

    float score = sab[0];

    #pragma unroll 1
    for (int half = 0; half < 2; ++half) {
        float acc[64];
        #pragma unroll
        for (int c = 0; c < 64; ++c) acc[c] = b2[half * 64 + c];

        #pragma unroll 1
        for (int kc = 0; kc < 8; ++kc) {
            float ph[32];
            #pragma unroll
            for (int j = 0; j < 32; ++j) ph[j] = b1[kc * 32 + j];

            #pragma unroll 1
            for (int k = 0; k < 153; ++k) {
                const float* xp = (k < 10) ? (body + k) : (k < 25) ? (objp + (k - 10)) : (ef + (k - 25));
                const float x = *xp;
                const float* wrow = W1 + k * 256 + kc * 32;
                #pragma unroll
                for (int j = 0; j < 32; ++j)
                    ph[j] = fmaf(x, wrow[j], ph[j]);
            }

            #pragma unroll
            for (int j = 0; j < 32; ++j) {
                const float hv = fmaxf(ph[j], 0.0f);
                const float* w = W2 + (kc * 32 + j) * 128 + half * 64;
                #pragma unroll
                for (int c = 0; c < 64; ++c)
                    acc[c] = fmaf(hv, w[c], acc[c]);
            }
        }

        float* prow = phi_ws + (size_t)t * 128 + half * 64;
        #pragma unroll
        for (int c = 0; c < 64; ++c) {
            acc[c] = fmaxf(acc[c], 0.0f);
            score = fmaf(acc[c], saW[half * 64 + c], score);
        }
        #pragma unroll
        for (int cc = 0; cc < 64; cc += 4) {
            float4 v = make_float4(acc[cc + 0], acc[cc + 1], acc[cc + 2], acc[cc + 3]);
            *reinterpret_cast<float4*>(prow + cc) = v;
        }
    }
    s_ws[t] = score;
}

// ---------------- Stage E: attention pool over 5 objects + rho + heads ----------------
__global__ __launch_bounds__(256) void kE(
    const float* __restrict__ phi_ws, const float* __restrict__ s_ws,
    const float* __restrict__ rhoT, const float* __restrict__ rho_b,
    const float* __restrict__ meanW, const float* __restrict__ meanb,
    const float* __restrict__ lsW, const float* __restrict__ lsb,
    float* __restrict__ outp)
{
    const int b = blockIdx.x * 256 + threadIdx.x;  // 0..16383

    float sc[5];
    #pragma unroll
    for (int o = 0; o < 5; ++o) sc[o] = s_ws[b * 5 + o];
    float m = sc[0];
    #pragma unroll
    for (int o = 1; o < 5; ++o) m = fmaxf(m, sc[o]);
    float aw[5];
    float den = 0.0f;
    #pragma unroll
    for (int o = 0; o < 5; ++o) { aw[o] = expf(sc[o] - m); den += aw[o]; }
    const float inv = 1.0f / den;

    float pooled[128];
    #pragma unroll
    for (int c = 0; c < 128; ++c) pooled[c] = 0.0f;

    #pragma unroll 1
    for (int o = 0; o < 5; ++o) {
        const float wgt = aw[o] * inv;
        const float* pr = phi_ws + ((size_t)b * 5 + o) * 128;
        #pragma unroll
        for (int c = 0; c < 128; ++c)
            pooled[c] = fmaf(wgt, pr[c], pooled[c]);
    }

    float macc[4], lacc[4];
    #pragma unroll
    for (int q = 0; q < 4; ++q) { macc[q] = meanb[q]; lacc[q] = lsb[q]; }

    #pragma unroll 1
    for (int j = 0; j < 256; ++j) {
        const float* wr = rhoT + j * 128;
        // 4 partial accumulators to break the dependent FMA chain
        float t0 = rho_b[j], t1 = 0.0f, t2 = 0.0f, t3 = 0.0f;
        #pragma unroll
        for (int k = 0; k < 128; k += 4) {
            t0 = fmaf(pooled[k + 0], wr[k + 0], t0);
            t1 = fmaf(pooled[k + 1], wr[k + 1], t1);
            t2 = fmaf(pooled[k + 2], wr[k + 2], t2);
            t3 = fmaf(pooled[k + 3], wr[k + 3], t3);
        }
        const float r = fmaxf((t0 + t1) + (t2 + t3), 0.0f);
        #pragma unroll
        for (int q = 0; q < 4; ++q) {
            macc[q] = fmaf(r, meanW[j * 4 + q], macc[q]);
            lacc[q] = fmaf(r, lsW[j * 4 + q], lacc[q]);
        }
    }

    float* mo = outp + (size_t)b * 4;
    float* lo = outp + (size_t)BATCH * 4 + (size_t)b * 4;
    #pragma unroll
    for (int q = 0; q < 4; ++q) {
        mo[q] = macc[q];
        lo[q] = fminf(fmaxf(lacc[q], -20.0f), 2.0f);
    }
}

extern "C" void kernel_launch(void* const* d_in, const int* in_sizes, int n_in,
                              void* d_out, int out_size, void* d_ws, size_t ws_size,
                              hipStream_t stream)
{
    const float* obs   = (const float*)d_in[0];
    const float* ag    = (const float*)d_in[1];
    const float* g     = (const float*)d_in[2];
    const float* mpW1  = (const float*)d_in[3];
    const float* mpb1  = (const float*)d_in[4];
    const float* mpW2  = (const float*)d_in[5];
    const float* mpb2  = (const float*)d_in[6];
    const float* eaW   = (const float*)d_in[7];
    const float* eab   = (const float*)d_in[8];
    const float* phW1  = (const float*)d_in[9];
    const float* phb1  = (const float*)d_in[10];
    const float* phW2  = (const float*)d_in[11];
    const float* phb2  = (const float*)d_in[12];
    const float* saW   = (const float*)d_in[13];
    const float* sab   = (const float*)d_in[14];
    const float* rhoW  = (const float*)d_in[15];
    const float* rhob  = (const float*)d_in[16];
    const float* meanW = (const float*)d_in[17];
    const float* meanb = (const float*)d_in[18];
    const float* lsW   = (const float*)d_in[19];
    const float* lsb   = (const float*)d_in[20];
    const int*   src   = (const int*)d_in[21];
    const int*   dst   = (const int*)d_in[22];
    const int*   inc   = (const int*)d_in[23];
    const int*   pred  = (const int*)d_in[24];

    // workspace layout (bytes):
    //  mp (bf16)  : [0, 83,886,080)
    //  e  (f32)   : [83,886,080, 85,196,800)
    //  edge (f32) : [85,196,800, 127,139,840)
    //  phi (f32)  : [127,139,840, 169,082,880)
    //  s  (f32)   : [169,082,880, 169,410,560)
    //  rhoT (f32) : [169,410,560, 169,541,632)
    char* ws = (char*)d_ws;
    u16*   mp_ws   = (u16*)(ws + 0);
    float* e_ws    = (float*)(ws + 83886080ull);
    float* edge_ws = (float*)(ws + 85196800ull);
    float* phi_ws  = (float*)(ws + 127139840ull);
    float* s_ws    = (float*)(ws + 169082880ull);
    float* rhoT    = (float*)(ws + 169410560ull);

    hipLaunchKernelGGL(kT, dim3(128), dim3(256), 0, stream, rhoW, rhoT);
    hipLaunchKernelGGL(kA, dim3(1280), dim3(256), 0, stream,
                       obs, ag, g, mpW1, mpb1, mpW2, mpb2, eaW, eab,
                       src, dst, pred, mp_ws, e_ws);
    hipLaunchKernelGGL(kB, dim3(320), dim3(256), 0, stream,
                       mp_ws, e_ws, inc, edge_ws);
    hipLaunchKernelGGL(kC, dim3(320), dim3(256), 0, stream,
                       obs, edge_ws, phW1, phb1, phW2, phb2, saW, sab,
                       phi_ws, s_ws);
    hipLaunchKernelGGL(kE, dim3(64), dim3(256), 0, stream,
                       phi_ws, s_ws, rhoT, rhob, meanW, meanb, lsW, lsb,
                       (float*)d_out);
}

// Round 2
// 242.638 us; speedup vs baseline: 8.6446x; 8.6446x over previous
//
#include <hip/hip_runtime.h>
#include <cstdint>
#include <cstddef>

typedef unsigned short u16;
typedef unsigned int u32;
typedef __attribute__((ext_vector_type(8))) short bf16x8;
typedef __attribute__((ext_vector_type(4))) float f32x4;

#define MFMA16(A, B, C) __builtin_amdgcn_mfma_f32_16x16x32_bf16((A), (B), (C), 0, 0, 0)

__device__ __forceinline__ u16 bf16_rne(float x) {
    u32 u = __float_as_uint(x);
    u += 0x7fffu + ((u >> 16) & 1u);
    return (u16)(u >> 16);
}
__device__ __forceinline__ float bf2f(u16 h) { return __uint_as_float((u32)h << 16); }
__device__ __forceinline__ u16 bf16_lo(float x, u16 hi) { return bf16_rne(x - bf2f(hi)); }
__device__ __forceinline__ float blo(u32 u) { return __uint_as_float(u << 16); }
__device__ __forceinline__ float bhi(u32 u) { return __uint_as_float(u & 0xffff0000u); }

// ---------------- weight packing into MFMA B-fragment order ----------------
// B-frag (16x16x32): lane l, elem i holds B[k = 8*(l>>4)+i][col = 16*tile + (l&15)]
// Bp1e: 16 tiles x 512 : 4-group trick  [w_hi, w_hi, w_lo, w_lo], src row = i
// Bp2e: [(c*8+n)*2+s][512] from mpW2 (256x128), s=0 hi / s=1 lo
// BpC1: [(c*2+s)*16+t][512] from phW1 (153x256), K permuted: 0..24 direct, 25..31 zero, 32..159 -> 25..152
// BpC2: same shape as Bp2e from phW2
__global__ __launch_bounds__(256) void PK(
    const float* __restrict__ mpW1, const float* __restrict__ mpW2,
    const float* __restrict__ phW1, const float* __restrict__ phW2,
    u16* __restrict__ Bp1e, u16* __restrict__ Bp2e,
    u16* __restrict__ BpC1, u16* __restrict__ BpC2)
{
    int tid = blockIdx.x * 256 + threadIdx.x;   // < 221184
    if (tid < 8192) {
        int t = tid >> 9, r = tid & 511;
        int l = r >> 3, i = r & 7, g = l >> 4, l15 = l & 15;
        float w = mpW1[i * 256 + 16 * t + l15];
        u16 h = bf16_rne(w);
        Bp1e[tid] = (g < 2) ? h : bf16_lo(w, h);
    } else if (tid < 8192 + 65536) {
        int f = tid - 8192;
        int b5 = f >> 9, r = f & 511;
        int l = r >> 3, i = r & 7, g = l >> 4, l15 = l & 15;
        int s = b5 & 1, cn = b5 >> 1, c = cn >> 3, n = cn & 7;
        int kk = 32 * c + 8 * g + i;
        float w = mpW2[kk * 128 + 16 * n + l15];
        u16 h = bf16_rne(w);
        Bp2e[f] = s ? bf16_lo(w, h) : h;
    } else if (tid < 8192 + 65536 + 81920) {
        int f = tid - 8192 - 65536;
        int b5 = f >> 9, r = f & 511;
        int l = r >> 3, i = r & 7, g = l >> 4, l15 = l & 15;
        int t = b5 & 15, cs = b5 >> 4, s = cs & 1, c = cs >> 1;
        int kk = 32 * c + 8 * g + i;
        int kp = kk < 25 ? kk : (kk < 32 ? -1 : kk - 7);
        float w = (kp < 0) ? 0.0f : phW1[kp * 256 + 16 * t + l15];
        u16 h = bf16_rne(w);
        BpC1[f] = s ? bf16_lo(w, h) : h;
    } else {
        int f = tid - 8192 - 65536 - 81920;
        int b5 = f >> 9, r = f & 511;
        int l = r >> 3, i = r & 7, g = l >> 4, l15 = l & 15;
        int s = b5 & 1, cn = b5 >> 1, c = cn >> 3, n = cn & 7;
        int kk = 32 * c + 8 * g + i;
        float w = phW2[kk * 128 + 16 * n + l15];
        u16 h = bf16_rne(w);
        BpC2[f] = s ? bf16_lo(w, h) : h;
    }
}

// ---------------- P1: build edge-MLP input rows, hi/lo 4-group packed ----------------
// Ein[row][32] bf16 : [x_hi(8) | x_lo(8) | x_hi(8) | x_lo(8)]
__global__ __launch_bounds__(256) void P1(
    const float* __restrict__ obs, const float* __restrict__ ag, const float* __restrict__ g,
    const int* __restrict__ src, const int* __restrict__ dst, const int* __restrict__ pred,
    u16* __restrict__ Ein)
{
    int row = blockIdx.x * 256 + threadIdx.x;   // < 327680
    int b = row / 20, p = row - b * 20;
    float inp[8];
    int i0 = pred[2 * p], i1 = pred[2 * p + 1];
    const float* gb = g + (size_t)b * 40;
    const float* ab = ag + (size_t)b * 40;
    inp[0] = gb[i0] - ab[i0];
    inp[1] = gb[i1] - ab[i1];
    int so = src[p], dd = dst[p];
    const float* ob = obs + (size_t)b * 85 + 10;
    inp[2] = ob[so * 15 + 0]; inp[3] = ob[so * 15 + 1]; inp[4] = ob[so * 15 + 2];
    inp[5] = ob[dd * 15 + 0]; inp[6] = ob[dd * 15 + 1]; inp[7] = ob[dd * 15 + 2];

    u32 wh[4], wl[4];
    #pragma unroll
    for (int k = 0; k < 4; ++k) {
        u16 h0 = bf16_rne(inp[2 * k]), h1 = bf16_rne(inp[2 * k + 1]);
        u16 l0 = bf16_lo(inp[2 * k], h0), l1 = bf16_lo(inp[2 * k + 1], h1);
        wh[k] = (u32)h0 | ((u32)h1 << 16);
        wl[k] = (u32)l0 | ((u32)l1 << 16);
    }
    uint4* d4 = (uint4*)(Ein + (size_t)row * 32);
    uint4 vh = make_uint4(wh[0], wh[1], wh[2], wh[3]);
    uint4 vl = make_uint4(wl[0], wl[1], wl[2], wl[3]);
    d4[0] = vh; d4[1] = vl; d4[2] = vh; d4[3] = vl;
}

// ---------------- GA: fused edge MLP (L1 -> LDS -> L2), MFMA ----------------
__global__ __launch_bounds__(512) void GA(
    const u16* __restrict__ Ein, const u16* __restrict__ Bp1, const u16* __restrict__ Bp2,
    const float* __restrict__ b1, const float* __restrict__ b2,
    const float* __restrict__ eaW, const float* __restrict__ eab,
    u16* __restrict__ mp, float* __restrict__ e_ws)
{
    __shared__ u16 hbuf[64 * 256];          // 32 KB, XOR-swizzled bf16
    __shared__ float spart[8][64];
    const int tid = threadIdx.x;
    const int w = tid >> 6, lane = tid & 63;
    const int l15 = lane & 15, gq = lane >> 4;
    const int rowbase = blockIdx.x * 64;

    // ---- stage 1: K=32 (exact product via 4-group hi/lo), tiles 2w, 2w+1 ----
    bf16x8 B1[2];
    float b1v[2];
    #pragma unroll
    for (int t = 0; t < 2; ++t) {
        B1[t] = *(const bf16x8*)(Bp1 + (size_t)(2 * w + t) * 512 + lane * 8);
        b1v[t] = b1[16 * (2 * w + t) + l15];
    }
    #pragma unroll 1
    for (int m = 0; m < 4; ++m) {
        const bf16x8 A = *(const bf16x8*)(Ein + (size_t)(rowbase + m * 16 + l15) * 32 + 8 * gq);
        #pragma unroll
        for (int t = 0; t < 2; ++t) {
            f32x4 acc = {0.f, 0.f, 0.f, 0.f};
            acc = MFMA16(A, B1[t], acc);
            const int col = 16 * (2 * w + t) + l15;
            #pragma unroll
            for (int j = 0; j < 4; ++j) {
                float v = fmaxf(acc[j] + b1v[t], 0.f);
                int row = m * 16 + 4 * gq + j;
                int byte = (row * 512 + col * 2) ^ ((row & 7) << 4);
                *(u16*)((char*)hbuf + byte) = bf16_rne(v);
            }
        }
    }
    __syncthreads();

    // ---- stage 2: K=256 (8 chunks x {w_hi,w_lo}), wave owns tile n=w ----
    bf16x8 B2[8][2];
    #pragma unroll
    for (int c = 0; c < 8; ++c)
        #pragma unroll
        for (int s = 0; s < 2; ++s)
            B2[c][s] = *(const bf16x8*)(Bp2 + (size_t)((c * 8 + w) * 2 + s) * 512 + lane * 8);
    const float b2v = b2[16 * w + l15];
    const float eav = eaW[16 * w + l15];

    #pragma unroll 1
    for (int m = 0; m < 4; ++m) {
        f32x4 acc = {0.f, 0.f, 0.f, 0.f};
        const int arow = m * 16 + l15;
        #pragma unroll
        for (int c = 0; c < 8; ++c) {
            int byte = (arow * 512 + c * 64 + gq * 16) ^ ((arow & 7) << 4);
            const bf16x8 A = *(const bf16x8*)((const char*)hbuf + byte);
            acc = MFMA16(A, B2[c][0], acc);
            acc = MFMA16(A, B2[c][1], acc);
        }
        #pragma unroll
        for (int j = 0; j < 4; ++j) {
            float v = fmaxf(acc[j] + b2v, 0.f);
            mp[(size_t)(rowbase + m * 16 + 4 * gq + j) * 128 + 16 * w + l15] = bf16_rne(v);
            float p = v * eav;
            p += __shfl_xor(p, 1, 64);
            p += __shfl_xor(p, 2, 64);
            p += __shfl_xor(p, 4, 64);
            p += __shfl_xor(p, 8, 64);
            if (l15 == 0) spart[w][m * 16 + 4 * gq + j] = p;
        }
    }
    __syncthreads();
    if (tid < 64) {
        float s = eab[0];
        #pragma unroll
        for (int ww = 0; ww < 8; ++ww) s += spart[ww][tid];
        e_ws[rowbase + tid] = s;
    }
}

// ---------------- KB: softmax over 4 incoming edges + weighted sum -> N_in cols 32..159 ----------------
__global__ __launch_bounds__(256) void KB(
    const u16* __restrict__ mp, const float* __restrict__ e_ws,
    const int* __restrict__ inc, u16* __restrict__ Nin)
{
    int idx = blockIdx.x * 256 + threadIdx.x;   // < 327680
    int q = idx & 3, t2 = idx >> 2;
    int b = t2 / 5, o = t2 - b * 5;

    int r[4]; float sc[4];
    #pragma unroll
    for (int i = 0; i < 4; ++i) {
        r[i] = b * 20 + inc[o * 4 + i];
        sc[i] = e_ws[r[i]];
    }
    float m = fmaxf(fmaxf(sc[0], sc[1]), fmaxf(sc[2], sc[3]));
    float wgt[4]; float den = 0.f;
    #pragma unroll
    for (int i = 0; i < 4; ++i) { wgt[i] = __expf(sc[i] - m); den += wgt[i]; }
    float inv = 1.0f / den;
    #pragma unroll
    for (int i = 0; i < 4; ++i) wgt[i] *= inv;

    float acc[32];
    #pragma unroll
    for (int e = 0; e < 32; ++e) acc[e] = 0.f;
    #pragma unroll
    for (int i = 0; i < 4; ++i) {
        const uint4* mrow = (const uint4*)(mp + (size_t)r[i] * 128 + 32 * q);
        const float wi = wgt[i];
        #pragma unroll
        for (int v4 = 0; v4 < 4; ++v4) {
            uint4 vv = mrow[v4];
            acc[v4 * 8 + 0] = fmaf(wi, blo(vv.x), acc[v4 * 8 + 0]);
            acc[v4 * 8 + 1] = fmaf(wi, bhi(vv.x), acc[v4 * 8 + 1]);
            acc[v4 * 8 + 2] = fmaf(wi, blo(vv.y), acc[v4 * 8 + 2]);
            acc[v4 * 8 + 3] = fmaf(wi, bhi(vv.y), acc[v4 * 8 + 3]);
            acc[v4 * 8 + 4] = fmaf(wi, blo(vv.z), acc[v4 * 8 + 4]);
            acc[v4 * 8 + 5] = fmaf(wi, bhi(vv.z), acc[v4 * 8 + 5]);
            acc[v4 * 8 + 6] = fmaf(wi, blo(vv.w), acc[v4 * 8 + 6]);
            acc[v4 * 8 + 7] = fmaf(wi, bhi(vv.w), acc[v4 * 8 + 7]);
        }
    }
    u32 wvs[16];
    #pragma unroll
    for (int k = 0; k < 16; ++k)
        wvs[k] = (u32)bf16_rne(acc[2 * k]) | ((u32)bf16_rne(acc[2 * k + 1]) << 16);
    uint4* d4 = (uint4*)(Nin + (size_t)t2 * 160 + 32 + 32 * q);
    d4[0] = make_uint4(wvs[0], wvs[1], wvs[2], wvs[3]);
    d4[1] = make_uint4(wvs[4], wvs[5], wvs[6], wvs[7]);
    d4[2] = make_uint4(wvs[8], wvs[9], wvs[10], wvs[11]);
    d4[3] = make_uint4(wvs[12], wvs[13], wvs[14], wvs[15]);
}

// ---------------- P2: N_in cols 0..31 (body, obj, zero pad) ----------------
__global__ __launch_bounds__(256) void P2(const float* __restrict__ obs, u16* __restrict__ Nin)
{
    int t = blockIdx.x * 256 + threadIdx.x;   // < 81920
    int b = t / 5, o = t - b * 5;
    const float* body = obs + (size_t)b * 85;
    const float* op = body + 10 + o * 15;
    u16 v[32];
    #pragma unroll
    for (int k = 0; k < 10; ++k) v[k] = bf16_rne(body[k]);
    #pragma unroll
    for (int k = 0; k < 15; ++k) v[10 + k] = bf16_rne(op[k]);
    #pragma unroll
    for (int k = 25; k < 32; ++k) v[k] = 0;
    u32 wvs[16];
    #pragma unroll
    for (int k = 0; k < 16; ++k) wvs[k] = (u32)v[2 * k] | ((u32)v[2 * k + 1] << 16);
    uint4* d4 = (uint4*)(Nin + (size_t)t * 160);
    d4[0] = make_uint4(wvs[0], wvs[1], wvs[2], wvs[3]);
    d4[1] = make_uint4(wvs[4], wvs[5], wvs[6], wvs[7]);
    d4[2] = make_uint4(wvs[8], wvs[9], wvs[10], wvs[11]);
    d4[3] = make_uint4(wvs[12], wvs[13], wvs[14], wvs[15]);
}

// ---------------- GB: fused node MLP (L1 -> LDS -> L2), MFMA ----------------
__global__ __launch_bounds__(512) void GB(
    const u16* __restrict__ Nin, const u16* __restrict__ BpC1, const u16* __restrict__ BpC2,
    const float* __restrict__ b1, const float* __restrict__ b2,
    const float* __restrict__ saW, const float* __restrict__ sab,
    float* __restrict__ phi, float* __restrict__ s_ws)
{
    __shared__ u16 hbuf[64 * 256];
    __shared__ float spart[8][64];
    const int tid = threadIdx.x;
    const int w = tid >> 6, lane = tid & 63;
    const int l15 = lane & 15, gq = lane >> 4;
    const int rowbase = blockIdx.x * 64;

    // ---- stage 1: K=160 (5 chunks x {w_hi,w_lo}), tiles 2w, 2w+1 ----
    bf16x8 BC[5][2][2];
    float b1v[2];
    #pragma unroll
    for (int t = 0; t < 2; ++t) b1v[t] = b1[16 * (2 * w + t) + l15];
    #pragma unroll
    for (int c = 0; c < 5; ++c)
        #pragma unroll
        for (int s = 0; s < 2; ++s)
            #pragma unroll
            for (int t = 0; t < 2; ++t)
                BC[c][s][t] = *(const bf16x8*)(BpC1 + (size_t)((c * 2 + s) * 16 + 2 * w + t) * 512 + lane * 8);

    #pragma unroll 1
    for (int m = 0; m < 4; ++m) {
        f32x4 a0 = {0.f, 0.f, 0.f, 0.f};
        f32x4 a1 = {0.f, 0.f, 0.f, 0.f};
        #pragma unroll
        for (int c = 0; c < 5; ++c) {
            const bf16x8 A = *(const bf16x8*)(Nin + (size_t)(rowbase + m * 16 + l15) * 160 + 32 * c + 8 * gq);
            a0 = MFMA16(A, BC[c][0][0], a0);
            a0 = MFMA16(A, BC[c][1][0], a0);
            a1 = MFMA16(A, BC[c][0][1], a1);
            a1 = MFMA16(A, BC[c][1][1], a1);
        }
        #pragma unroll
        for (int j = 0; j < 4; ++j) {
            int row = m * 16 + 4 * gq + j;
            {
                float v = fmaxf(a0[j] + b1v[0], 0.f);
                int col = 16 * (2 * w + 0) + l15;
                int byte = (row * 512 + col * 2) ^ ((row & 7) << 4);
                *(u16*)((char*)hbuf + byte) = bf16_rne(v);
            }
            {
                float v = fmaxf(a1[j] + b1v[1], 0.f);
                int col = 16 * (2 * w + 1) + l15;
                int byte = (row * 512 + col * 2) ^ ((row & 7) << 4);
                *(u16*)((char*)hbuf + byte) = bf16_rne(v);
            }
        }
    }
    __syncthreads();

    // ---- stage 2: K=256, wave owns tile n=w ----
    bf16x8 B2[8][2];
    #pragma unroll
    for (int c = 0; c < 8; ++c)
        #pragma unroll
        for (int s = 0; s < 2; ++s)
            B2[c][s] = *(const bf16x8*)(BpC2 + (size_t)((c * 8 + w) * 2 + s) * 512 + lane * 8);
    const float b2v = b2[16 * w + l15];
    const float sav = saW[16 * w + l15];

    #pragma unroll 1
    for (int m = 0; m < 4; ++m) {
        f32x4 acc = {0.f, 0.f, 0.f, 0.f};
        const int arow = m * 16 + l15;
        #pragma unroll
        for (int c = 0; c < 8; ++c) {
            int byte = (arow * 512 + c * 64 + gq * 16) ^ ((arow & 7) << 4);
            const bf16x8 A = *(const bf16x8*)((const char*)hbuf + byte);
            acc = MFMA16(A, B2[c][0], acc);
            acc = MFMA16(A, B2[c][1], acc);
        }
        #pragma unroll
        for (int j = 0; j < 4; ++j) {
            float v = fmaxf(acc[j] + b2v, 0.f);
            phi[(size_t)(rowbase + m * 16 + 4 * gq + j) * 128 + 16 * w + l15] = v;
            float p = v * sav;
            p += __shfl_xor(p, 1, 64);
            p += __shfl_xor(p, 2, 64);
            p += __shfl_xor(p, 4, 64);
            p += __shfl_xor(p, 8, 64);
            if (l15 == 0) spart[w][m * 16 + 4 * gq + j] = p;
        }
    }
    __syncthreads();
    if (tid < 64) {
        float s = sab[0];
        #pragma unroll
        for (int ww = 0; ww < 8; ++ww) s += spart[ww][tid];
        s_ws[rowbase + tid] = s;
    }
}

// ---------------- KE: attention pool + rho + heads, one wave per batch row ----------------
__global__ __launch_bounds__(256) void KE(
    const float* __restrict__ phi, const float* __restrict__ s_ws,
    const float* __restrict__ rhoW, const float* __restrict__ rhob,
    const float* __restrict__ meanW, const float* __restrict__ meanb,
    const float* __restrict__ lsW, const float* __restrict__ lsb,
    float* __restrict__ outp)
{
    __shared__ float pool[4][128];
    const int w = threadIdx.x >> 6, lane = threadIdx.x & 63;
    const int b = blockIdx.x * 4 + w;

    float sc[5];
    #pragma unroll
    for (int o = 0; o < 5; ++o) sc[o] = s_ws[b * 5 + o];
    float m = sc[0];
    #pragma unroll
    for (int o = 1; o < 5; ++o) m = fmaxf(m, sc[o]);
    float aw[5]; float den = 0.f;
    #pragma unroll
    for (int o = 0; o < 5; ++o) { aw[o] = __expf(sc[o] - m); den += aw[o]; }
    const float inv = 1.0f / den;

    float p0 = 0.f, p1 = 0.f;
    #pragma unroll
    for (int o = 0; o < 5; ++o) {
        const float wo = aw[o] * inv;
        const float* pr = phi + (size_t)(b * 5 + o) * 128;
        p0 = fmaf(wo, pr[lane], p0);
        p1 = fmaf(wo, pr[lane + 64], p1);
    }
    pool[w][lane] = p0;
    pool[w][lane + 64] = p1;
    __syncthreads();

    float racc[4];
    #pragma unroll
    for (int q = 0; q < 4; ++q) racc[q] = rhob[4 * lane + q];
    #pragma unroll 8
    for (int k = 0; k < 128; ++k) {
        const float x = pool[w][k];
        const float4 wr = *(const float4*)(rhoW + (size_t)k * 256 + 4 * lane);
        racc[0] = fmaf(x, wr.x, racc[0]);
        racc[1] = fmaf(x, wr.y, racc[1]);
        racc[2] = fmaf(x, wr.z, racc[2]);
        racc[3] = fmaf(x, wr.w, racc[3]);
    }
    #pragma unroll
    for (int q = 0; q < 4; ++q) racc[q] = fmaxf(racc[q], 0.f);

    float macc[4] = {0.f, 0.f, 0.f, 0.f};
    float lacc[4] = {0.f, 0.f, 0.f, 0.f};
    #pragma unroll
    for (int jj = 0; jj < 4; ++jj) {
        const float r = racc[jj];
        const float4 mw = *(const float4*)(meanW + (size_t)(4 * lane + jj) * 4);
        const float4 lw = *(const float4*)(lsW + (size_t)(4 * lane + jj) * 4);
        macc[0] = fmaf(r, mw.x, macc[0]); macc[1] = fmaf(r, mw.y, macc[1]);
        macc[2] = fmaf(r, mw.z, macc[2]); macc[3] = fmaf(r, mw.w, macc[3]);
        lacc[0] = fmaf(r, lw.x, lacc[0]); lacc[1] = fmaf(r, lw.y, lacc[1]);
        lacc[2] = fmaf(r, lw.z, lacc[2]); lacc[3] = fmaf(r, lw.w, lacc[3]);
    }
    #pragma unroll
    for (int mask = 1; mask < 64; mask <<= 1) {
        #pragma unroll
        for (int q = 0; q < 4; ++q) {
            macc[q] += __shfl_xor(macc[q], mask, 64);
            lacc[q] += __shfl_xor(lacc[q], mask, 64);
        }
    }
    if (lane == 0) {
        #pragma unroll
        for (int q = 0; q < 4; ++q) {
            outp[(size_t)b * 4 + q] = macc[q] + meanb[q];
            float l = lacc[q] + lsb[q];
            outp[65536 + (size_t)b * 4 + q] = fminf(fmaxf(l, -20.0f), 2.0f);
        }
    }
}

extern "C" void kernel_launch(void* const* d_in, const int* in_sizes, int n_in,
                              void* d_out, int out_size, void* d_ws, size_t ws_size,
                              hipStream_t stream)
{
    const float* obs   = (const float*)d_in[0];
    const float* ag    = (const float*)d_in[1];
    const float* g     = (const float*)d_in[2];
    const float* mpW1  = (const float*)d_in[3];
    const float* mpb1  = (const float*)d_in[4];
    const float* mpW2  = (const float*)d_in[5];
    const float* mpb2  = (const float*)d_in[6];
    const float* eaW   = (const float*)d_in[7];
    const float* eab   = (const float*)d_in[8];
    const float* phW1  = (const float*)d_in[9];
    const float* phb1  = (const float*)d_in[10];
    const float* phW2  = (const float*)d_in[11];
    const float* phb2  = (const float*)d_in[12];
    const float* saW   = (const float*)d_in[13];
    const float* sab   = (const float*)d_in[14];
    const float* rhoW  = (const float*)d_in[15];
    const float* rhob  = (const float*)d_in[16];
    const float* meanW = (const float*)d_in[17];
    const float* meanb = (const float*)d_in[18];
    const float* lsW   = (const float*)d_in[19];
    const float* lsb   = (const float*)d_in[20];
    const int*   src   = (const int*)d_in[21];
    const int*   dst   = (const int*)d_in[22];
    const int*   inc   = (const int*)d_in[23];
    const int*   pred  = (const int*)d_in[24];

    // workspace layout (bytes), total 133,152,768:
    //  mp (u16 327680x128) : [0, 83886080)          -- dead after KB
    //  phi (f32 81920x128) : [0, 41943040)          -- ALIASES mp (written by GB after KB)
    //  e_ws (f32 327680)   : [83886080, 85196800)
    //  Ein (u16 327680x32) : [85196800, 106168320)
    //  Nin (u16 81920x160) : [106168320, 132382720)
    //  s_ws (f32 81920)    : [132382720, 132710400)
    //  Bp1e (u16 8192)     : [132710400, 132726784)
    //  Bp2e (u16 65536)    : [132726784, 132857856)
    //  BpC1 (u16 81920)    : [132857856, 133021696)
    //  BpC2 (u16 65536)    : [133021696, 133152768)
    char* ws = (char*)d_ws;
    u16*   mp_ws = (u16*)(ws + 0);
    float* phi_ws = (float*)(ws + 0);
    float* e_ws  = (float*)(ws + 83886080ull);
    u16*   Ein   = (u16*)(ws + 85196800ull);
    u16*   Nin   = (u16*)(ws + 106168320ull);
    float* s_ws  = (float*)(ws + 132382720ull);
    u16*   Bp1e  = (u16*)(ws + 132710400ull);
    u16*   Bp2e  = (u16*)(ws + 132726784ull);
    u16*   BpC1  = (u16*)(ws + 132857856ull);
    u16*   BpC2  = (u16*)(ws + 133021696ull);

    hipLaunchKernelGGL(PK, dim3(864), dim3(256), 0, stream,
                       mpW1, mpW2, phW1, phW2, Bp1e, Bp2e, BpC1, BpC2);
    hipLaunchKernelGGL(P1, dim3(1280), dim3(256), 0, stream,
                       obs, ag, g, src, dst, pred, Ein);
    hipLaunchKernelGGL(GA, dim3(5120), dim3(512), 0, stream,
                       Ein, Bp1e, Bp2e, mpb1, mpb2, eaW, eab, mp_ws, e_ws);
    hipLaunchKernelGGL(KB, dim3(1280), dim3(256), 0, stream,
                       mp_ws, e_ws, inc, Nin);
    hipLaunchKernelGGL(P2, dim3(320), dim3(256), 0, stream, obs, Nin);
    hipLaunchKernelGGL(GB, dim3(1280), dim3(512), 0, stream,
                       Nin, BpC1, BpC2, phb1, phb2, saW, sab, phi_ws, s_ws);
    hipLaunchKernelGGL(KE, dim3(4096), dim3(256), 0, stream,
                       phi_ws, s_ws, rhoW, rhob, meanW, meanb, lsW, lsb,
                       (float*)d_out);
}

// Round 3
// 167.438 us; speedup vs baseline: 12.5271x; 1.4491x over previous
//
#include <hip/hip_runtime.h>
#include <cstdint>
#include <cstddef>

typedef unsigned short u16;
typedef unsigned int u32;
typedef __attribute__((ext_vector_type(8))) short bf16x8;
typedef __attribute__((ext_vector_type(4))) float f32x4;

#define MFMA16(A, B, C) __builtin_amdgcn_mfma_f32_16x16x32_bf16((A), (B), (C), 0, 0, 0)

__device__ __forceinline__ u16 bf16_rne(float x) {
    u32 u = __float_as_uint(x);
    u += 0x7fffu + ((u >> 16) & 1u);
    return (u16)(u >> 16);
}
__device__ __forceinline__ float bf2f(u16 h) { return __uint_as_float((u32)h << 16); }
__device__ __forceinline__ u16 bf16_lo(float x, u16 hi) { return bf16_rne(x - bf2f(hi)); }
__device__ __forceinline__ float blo(u32 u) { return __uint_as_float(u << 16); }
__device__ __forceinline__ float bhi(u32 u) { return __uint_as_float(u & 0xffff0000u); }

// ================= PK: pack all weights into MFMA B-fragment order =================
// B-frag (16x16x32): lane l, elem i holds B[k = 8*(l>>4)+i][col = 16*tile + (l&15)]
__global__ __launch_bounds__(256) void PK(
    const float* __restrict__ mpW1, const float* __restrict__ mpW2,
    const float* __restrict__ phW1, const float* __restrict__ phW2,
    const float* __restrict__ rhoW,
    u16* __restrict__ Bp1e, u16* __restrict__ Bp2e,
    u16* __restrict__ BpC1, u16* __restrict__ BpC2, u16* __restrict__ BpR)
{
    int tid = blockIdx.x * 256 + threadIdx.x;   // < 286720
    if (tid < 8192) {
        // edge L1: 16 tiles x 512, 4-group trick [w_hi, w_hi, w_lo, w_lo]
        int t = tid >> 9, r = tid & 511;
        int l = r >> 3, i = r & 7, g = l >> 4, l15 = l & 15;
        float w = mpW1[i * 256 + 16 * t + l15];
        u16 h = bf16_rne(w);
        Bp1e[tid] = (g < 2) ? h : bf16_lo(w, h);
    } else if (tid < 73728) {
        // edge L2: [(c*8+n)*2+s][512] from mpW2 (256x128)
        int f = tid - 8192;
        int b5 = f >> 9, r = f & 511;
        int l = r >> 3, i = r & 7, g = l >> 4, l15 = l & 15;
        int s = b5 & 1, cn = b5 >> 1, c = cn >> 3, n = cn & 7;
        int kk = 32 * c + 8 * g + i;
        float w = mpW2[kk * 128 + 16 * n + l15];
        u16 h = bf16_rne(w);
        Bp2e[f] = s ? bf16_lo(w, h) : h;
    } else if (tid < 155648) {
        // node L1: [(c*2+s)*16+t][512] from phW1 (153x256), K perm: 0..24 direct, 25..31 zero, 32..159 -> 25..152
        int f = tid - 73728;
        int b5 = f >> 9, r = f & 511;
        int l = r >> 3, i = r & 7, g = l >> 4, l15 = l & 15;
        int t = b5 & 15, cs = b5 >> 4, s = cs & 1, c = cs >> 1;
        int kk = 32 * c + 8 * g + i;
        int kp = kk < 25 ? kk : (kk < 32 ? -1 : kk - 7);
        float w = (kp < 0) ? 0.0f : phW1[kp * 256 + 16 * t + l15];
        u16 h = bf16_rne(w);
        BpC1[f] = s ? bf16_lo(w, h) : h;
    } else if (tid < 221184) {
        // node L2: same shape as edge L2, from phW2 (256x128)
        int f = tid - 155648;
        int b5 = f >> 9, r = f & 511;
        int l = r >> 3, i = r & 7, g = l >> 4, l15 = l & 15;
        int s = b5 & 1, cn = b5 >> 1, c = cn >> 3, n = cn & 7;
        int kk = 32 * c + 8 * g + i;
        float w = phW2[kk * 128 + 16 * n + l15];
        u16 h = bf16_rne(w);
        BpC2[f] = s ? bf16_lo(w, h) : h;
    } else {
        // rho: [(c*16+t)*2+s][512] from rhoW (128x256), c<4 (K=128), t<16 (N=256)
        int f = tid - 221184;
        int b5 = f >> 9, r = f & 511;
        int l = r >> 3, i = r & 7, g = l >> 4, l15 = l & 15;
        int s = b5 & 1, ct = b5 >> 1, c = ct >> 4, t = ct & 15;
        int kk = 32 * c + 8 * g + i;
        float w = rhoW[kk * 256 + 16 * t + l15];
        u16 h = bf16_rne(w);
        BpR[f] = s ? bf16_lo(w, h) : h;
    }
}

// ================= P1: edge-MLP input rows, hi/lo 4-group packed =================
// Ein[row][32] bf16 : [x_hi(8) | x_lo(8) | x_hi(8) | x_lo(8)]
__global__ __launch_bounds__(256) void P1(
    const float* __restrict__ obs, const float* __restrict__ ag, const float* __restrict__ g,
    const int* __restrict__ src, const int* __restrict__ dst, const int* __restrict__ pred,
    u16* __restrict__ Ein)
{
    int row = blockIdx.x * 256 + threadIdx.x;   // < 327680
    int b = row / 20, p = row - b * 20;
    float inp[8];
    int i0 = pred[2 * p], i1 = pred[2 * p + 1];
    const float* gb = g + (size_t)b * 40;
    const float* ab = ag + (size_t)b * 40;
    inp[0] = gb[i0] - ab[i0];
    inp[1] = gb[i1] - ab[i1];
    int so = src[p], dd = dst[p];
    const float* ob = obs + (size_t)b * 85 + 10;
    inp[2] = ob[so * 15 + 0]; inp[3] = ob[so * 15 + 1]; inp[4] = ob[so * 15 + 2];
    inp[5] = ob[dd * 15 + 0]; inp[6] = ob[dd * 15 + 1]; inp[7] = ob[dd * 15 + 2];

    u32 wh[4], wl[4];
    #pragma unroll
    for (int k = 0; k < 4; ++k) {
        u16 h0 = bf16_rne(inp[2 * k]), h1 = bf16_rne(inp[2 * k + 1]);
        u16 l0 = bf16_lo(inp[2 * k], h0), l1 = bf16_lo(inp[2 * k + 1], h1);
        wh[k] = (u32)h0 | ((u32)h1 << 16);
        wl[k] = (u32)l0 | ((u32)l1 << 16);
    }
    uint4* d4 = (uint4*)(Ein + (size_t)row * 32);
    uint4 vh = make_uint4(wh[0], wh[1], wh[2], wh[3]);
    uint4 vl = make_uint4(wl[0], wl[1], wl[2], wl[3]);
    d4[0] = vh; d4[1] = vl; d4[2] = vh; d4[3] = vl;
}

// ================= P2: Nin cols 0..31 (body, obj, zero pad) =================
__global__ __launch_bounds__(256) void P2(const float* __restrict__ obs, u16* __restrict__ Nin)
{
    int t = blockIdx.x * 256 + threadIdx.x;   // < 81920
    int b = t / 5, o = t - b * 5;
    const float* body = obs + (size_t)b * 85;
    const float* op = body + 10 + o * 15;
    u16 v[32];
    #pragma unroll
    for (int k = 0; k < 10; ++k) v[k] = bf16_rne(body[k]);
    #pragma unroll
    for (int k = 0; k < 15; ++k) v[10 + k] = bf16_rne(op[k]);
    #pragma unroll
    for (int k = 25; k < 32; ++k) v[k] = 0;
    u32 wvs[16];
    #pragma unroll
    for (int k = 0; k < 16; ++k) wvs[k] = (u32)v[2 * k] | ((u32)v[2 * k + 1] << 16);
    uint4* d4 = (uint4*)(Nin + (size_t)t * 160);
    d4[0] = make_uint4(wvs[0], wvs[1], wvs[2], wvs[3]);
    d4[1] = make_uint4(wvs[4], wvs[5], wvs[6], wvs[7]);
    d4[2] = make_uint4(wvs[8], wvs[9], wvs[10], wvs[11]);
    d4[3] = make_uint4(wvs[12], wvs[13], wvs[14], wvs[15]);
}

// ================= GA2: fused edge MLP + softmax-aggregate -> Nin[32..159] =================
// 80 rows/block = 4 batches; 512 threads = 8 waves.
__global__ __launch_bounds__(512) void GA(
    const u16* __restrict__ Ein, const u16* __restrict__ Bp1, const u16* __restrict__ Bp2,
    const float* __restrict__ b1, const float* __restrict__ b2,
    const float* __restrict__ eaW, const float* __restrict__ eab,
    const int* __restrict__ inc, u16* __restrict__ Nin)
{
    __shared__ u16 hb[2][16 * 256];     // 16 KB, double-buffered h tile, swizzled
    __shared__ u16 mpb[80 * 128];       // 20 KB, mp values, swizzled
    __shared__ float esc[80];
    __shared__ float wbuf[80];
    __shared__ int rowb[80];
    __shared__ float eaWL[128];
    __shared__ int incL[20];

    const int tid = threadIdx.x;
    const int w = tid >> 6, lane = tid & 63;
    const int l15 = lane & 15, gq = lane >> 4;
    const int rowbase = blockIdx.x * 80;
    char* hbc = (char*)hb;
    char* mpc = (char*)mpb;

    if (tid < 128) eaWL[tid] = eaW[tid];
    if (tid < 20) incL[tid] = inc[tid];

    // stage-1 B fragments (tiles 2w, 2w+1) + biases
    bf16x8 B1[2];
    float b1v[2];
    #pragma unroll
    for (int t = 0; t < 2; ++t) {
        B1[t] = *(const bf16x8*)(Bp1 + (size_t)(2 * w + t) * 512 + lane * 8);
        b1v[t] = b1[16 * (2 * w + t) + l15];
    }
    // stage-2 B fragments (tile n=w), hi/lo
    bf16x8 B2[8][2];
    #pragma unroll
    for (int c = 0; c < 8; ++c)
        #pragma unroll
        for (int s = 0; s < 2; ++s)
            B2[c][s] = *(const bf16x8*)(Bp2 + (size_t)((c * 8 + w) * 2 + s) * 512 + lane * 8);
    const float b2v = b2[16 * w + l15];

    // ---- stage1(m) into hb[buf] ----
    auto stage1 = [&](int m, int buf) {
        const bf16x8 A = *(const bf16x8*)(Ein + (size_t)(rowbase + m * 16 + l15) * 32 + 8 * gq);
        #pragma unroll
        for (int t = 0; t < 2; ++t) {
            f32x4 acc = {0.f, 0.f, 0.f, 0.f};
            acc = MFMA16(A, B1[t], acc);
            const int col = 16 * (2 * w + t) + l15;
            #pragma unroll
            for (int j = 0; j < 4; ++j) {
                float v = fmaxf(acc[j] + b1v[t], 0.f);
                int r16 = 4 * gq + j;
                int byte = buf * 8192 + ((r16 * 512 + col * 2) ^ ((r16 & 7) << 4));
                *(u16*)(hbc + byte) = bf16_rne(v);
            }
        }
    };
    // ---- stage2(m) from hb[buf] -> mpb ----
    auto stage2 = [&](int m, int buf) {
        f32x4 acc = {0.f, 0.f, 0.f, 0.f};
        #pragma unroll
        for (int c = 0; c < 8; ++c) {
            int byte = buf * 8192 + ((l15 * 512 + c * 64 + gq * 16) ^ ((l15 & 7) << 4));
            const bf16x8 A = *(const bf16x8*)(hbc + byte);
            acc = MFMA16(A, B2[c][0], acc);
            acc = MFMA16(A, B2[c][1], acc);
        }
        #pragma unroll
        for (int j = 0; j < 4; ++j) {
            float v = fmaxf(acc[j] + b2v, 0.f);
            int r = m * 16 + 4 * gq + j;
            int byte = (r * 256 + (16 * w + l15) * 2) ^ ((r & 15) << 4);
            *(u16*)(mpc + byte) = bf16_rne(v);
        }
    };

    stage1(0, 0);
    __syncthreads();
    #pragma unroll 1
    for (int m = 0; m < 5; ++m) {
        if (m < 4) stage1(m + 1, (m + 1) & 1);
        stage2(m, m & 1);
        __syncthreads();
    }

    // ---- e-pass: score per edge row ----
    if (tid < 80) {
        float e = eab[0];
        #pragma unroll
        for (int c = 0; c < 16; ++c) {
            int byte = (tid * 256 + c * 16) ^ ((tid & 15) << 4);
            uint4 v = *(const uint4*)(mpc + byte);
            e = fmaf(blo(v.x), eaWL[c * 8 + 0], e);
            e = fmaf(bhi(v.x), eaWL[c * 8 + 1], e);
            e = fmaf(blo(v.y), eaWL[c * 8 + 2], e);
            e = fmaf(bhi(v.y), eaWL[c * 8 + 3], e);
            e = fmaf(blo(v.z), eaWL[c * 8 + 4], e);
            e = fmaf(bhi(v.z), eaWL[c * 8 + 5], e);
            e = fmaf(blo(v.w), eaWL[c * 8 + 6], e);
            e = fmaf(bhi(v.w), eaWL[c * 8 + 7], e);
        }
        esc[tid] = e;
    }
    __syncthreads();

    // ---- softmax weights for 20 (batch,obj) pairs ----
    if (tid < 20) {
        int bl = tid / 5, o = tid - bl * 5;
        int rr[4]; float ee[4];
        #pragma unroll
        for (int i = 0; i < 4; ++i) {
            rr[i] = bl * 20 + incL[o * 4 + i];
            ee[i] = esc[rr[i]];
        }
        float mx = fmaxf(fmaxf(ee[0], ee[1]), fmaxf(ee[2], ee[3]));
        float ex[4]; float den = 0.f;
        #pragma unroll
        for (int i = 0; i < 4; ++i) { ex[i] = __expf(ee[i] - mx); den += ex[i]; }
        float inv = 1.0f / den;
        #pragma unroll
        for (int i = 0; i < 4; ++i) {
            wbuf[tid * 4 + i] = ex[i] * inv;
            rowb[tid * 4 + i] = rr[i];
        }
    }
    __syncthreads();

    // ---- phase3: weighted gather -> Nin cols 32..159 ----
    if (tid < 320) {
        int p = tid >> 4, cb = tid & 15;
        float acc[8] = {0, 0, 0, 0, 0, 0, 0, 0};
        #pragma unroll
        for (int i = 0; i < 4; ++i) {
            int r = rowb[p * 4 + i];
            float wi = wbuf[p * 4 + i];
            int byte = (r * 256 + cb * 16) ^ ((r & 15) << 4);
            uint4 v = *(const uint4*)(mpc + byte);
            acc[0] = fmaf(wi, blo(v.x), acc[0]);
            acc[1] = fmaf(wi, bhi(v.x), acc[1]);
            acc[2] = fmaf(wi, blo(v.y), acc[2]);
            acc[3] = fmaf(wi, bhi(v.y), acc[3]);
            acc[4] = fmaf(wi, blo(v.z), acc[4]);
            acc[5] = fmaf(wi, bhi(v.z), acc[5]);
            acc[6] = fmaf(wi, blo(v.w), acc[6]);
            acc[7] = fmaf(wi, bhi(v.w), acc[7]);
        }
        uint4 ov;
        ov.x = (u32)bf16_rne(acc[0]) | ((u32)bf16_rne(acc[1]) << 16);
        ov.y = (u32)bf16_rne(acc[2]) | ((u32)bf16_rne(acc[3]) << 16);
        ov.z = (u32)bf16_rne(acc[4]) | ((u32)bf16_rne(acc[5]) << 16);
        ov.w = (u32)bf16_rne(acc[6]) | ((u32)bf16_rne(acc[7]) << 16);
        int grow = blockIdx.x * 20 + p;
        *(uint4*)(Nin + (size_t)grow * 160 + 32 + cb * 8) = ov;
    }
}

// ================= GB2: fused node MLP + attn-pool + rho + heads -> out =================
// 80 rows/block = 16 batches; 512 threads = 8 waves.
__global__ __launch_bounds__(512) void GB(
    const u16* __restrict__ Nin, const u16* __restrict__ BpC1, const u16* __restrict__ BpC2,
    const u16* __restrict__ BpR,
    const float* __restrict__ b1, const float* __restrict__ b2,
    const float* __restrict__ saW, const float* __restrict__ sab,
    const float* __restrict__ rhob,
    const float* __restrict__ meanW, const float* __restrict__ meanb,
    const float* __restrict__ lsW, const float* __restrict__ lsb,
    float* __restrict__ outp)
{
    __shared__ u16 hb[2][16 * 256];      // 16 KB
    __shared__ float phibuf[80 * 132];   // 42.25 KB padded; later aliased as rbuf[16][260]
    __shared__ u32 poolw[16 * 132];      // 8.25 KB packed hi|lo bf16
    __shared__ float sbuf[80];
    __shared__ float awb[80];
    __shared__ float saWL[128];
    __shared__ float headW[2048];        // 8 KB  [k][q]: q<4 mean, q>=4 logstd
    __shared__ float rhobL[256];

    const int tid = threadIdx.x;
    const int w = tid >> 6, lane = tid & 63;
    const int l15 = lane & 15, gq = lane >> 4;
    const int rowbase = blockIdx.x * 80;
    char* hbc = (char*)hb;
    float* rbuf = phibuf;                // alias, stride 260 f32

    if (tid < 128) saWL[tid] = saW[tid];
    if (tid < 256) rhobL[tid] = rhob[tid];
    #pragma unroll
    for (int idx = tid; idx < 2048; idx += 512) {
        int k = idx >> 3, q = idx & 7;
        headW[idx] = (q < 4) ? meanW[k * 4 + q] : lsW[k * 4 + (q - 4)];
    }

    // stage-1 B frags: 5 chunks x {hi,lo} x 2 tiles
    bf16x8 BC[5][2][2];
    float b1v[2];
    #pragma unroll
    for (int t = 0; t < 2; ++t) b1v[t] = b1[16 * (2 * w + t) + l15];
    #pragma unroll
    for (int c = 0; c < 5; ++c)
        #pragma unroll
        for (int s = 0; s < 2; ++s)
            #pragma unroll
            for (int t = 0; t < 2; ++t)
                BC[c][s][t] = *(const bf16x8*)(BpC1 + (size_t)((c * 2 + s) * 16 + 2 * w + t) * 512 + lane * 8);
    // stage-2 B frags
    bf16x8 B2[8][2];
    #pragma unroll
    for (int c = 0; c < 8; ++c)
        #pragma unroll
        for (int s = 0; s < 2; ++s)
            B2[c][s] = *(const bf16x8*)(BpC2 + (size_t)((c * 8 + w) * 2 + s) * 512 + lane * 8);
    const float b2v = b2[16 * w + l15];

    auto stage1 = [&](int m, int buf) {
        f32x4 a0 = {0.f, 0.f, 0.f, 0.f};
        f32x4 a1 = {0.f, 0.f, 0.f, 0.f};
        #pragma unroll
        for (int c = 0; c < 5; ++c) {
            const bf16x8 A = *(const bf16x8*)(Nin + (size_t)(rowbase + m * 16 + l15) * 160 + 32 * c + 8 * gq);
            a0 = MFMA16(A, BC[c][0][0], a0);
            a0 = MFMA16(A, BC[c][1][0], a0);
            a1 = MFMA16(A, BC[c][0][1], a1);
            a1 = MFMA16(A, BC[c][1][1], a1);
        }
        #pragma unroll
        for (int j = 0; j < 4; ++j) {
            int r16 = 4 * gq + j;
            {
                float v = fmaxf(a0[j] + b1v[0], 0.f);
                int col = 16 * (2 * w + 0) + l15;
                int byte = buf * 8192 + ((r16 * 512 + col * 2) ^ ((r16 & 7) << 4));
                *(u16*)(hbc + byte) = bf16_rne(v);
            }
            {
                float v = fmaxf(a1[j] + b1v[1], 0.f);
                int col = 16 * (2 * w + 1) + l15;
                int byte = buf * 8192 + ((r16 * 512 + col * 2) ^ ((r16 & 7) << 4));
                *(u16*)(hbc + byte) = bf16_rne(v);
            }
        }
    };
    auto stage2 = [&](int m, int buf) {
        f32x4 acc = {0.f, 0.f, 0.f, 0.f};
        #pragma unroll
        for (int c = 0; c < 8; ++c) {
            int byte = buf * 8192 + ((l15 * 512 + c * 64 + gq * 16) ^ ((l15 & 7) << 4));
            const bf16x8 A = *(const bf16x8*)(hbc + byte);
            acc = MFMA16(A, B2[c][0], acc);
            acc = MFMA16(A, B2[c][1], acc);
        }
        #pragma unroll
        for (int j = 0; j < 4; ++j) {
            float v = fmaxf(acc[j] + b2v, 0.f);
            int r = m * 16 + 4 * gq + j;
            phibuf[r * 132 + 16 * w + l15] = v;
        }
    };

    stage1(0, 0);
    __syncthreads();
    #pragma unroll 1
    for (int m = 0; m < 5; ++m) {
        if (m < 4) stage1(m + 1, (m + 1) & 1);
        stage2(m, m & 1);
        __syncthreads();
    }

    // ---- s-pass: attention score per (b,o) row ----
    if (tid < 80) {
        float s = sab[0];
        #pragma unroll
        for (int c = 0; c < 32; ++c) {
            float4 v = *(const float4*)(phibuf + tid * 132 + c * 4);
            s = fmaf(v.x, saWL[c * 4 + 0], s);
            s = fmaf(v.y, saWL[c * 4 + 1], s);
            s = fmaf(v.z, saWL[c * 4 + 2], s);
            s = fmaf(v.w, saWL[c * 4 + 3], s);
        }
        sbuf[tid] = s;
    }
    __syncthreads();

    // ---- softmax over 5 objects per batch ----
    if (tid < 16) {
        float s0 = sbuf[tid * 5 + 0], s1 = sbuf[tid * 5 + 1], s2 = sbuf[tid * 5 + 2];
        float s3 = sbuf[tid * 5 + 3], s4 = sbuf[tid * 5 + 4];
        float mx = fmaxf(fmaxf(fmaxf(s0, s1), fmaxf(s2, s3)), s4);
        float e0 = __expf(s0 - mx), e1 = __expf(s1 - mx), e2 = __expf(s2 - mx);
        float e3 = __expf(s3 - mx), e4 = __expf(s4 - mx);
        float inv = 1.0f / (e0 + e1 + e2 + e3 + e4);
        awb[tid * 5 + 0] = e0 * inv; awb[tid * 5 + 1] = e1 * inv;
        awb[tid * 5 + 2] = e2 * inv; awb[tid * 5 + 3] = e3 * inv;
        awb[tid * 5 + 4] = e4 * inv;
    }
    __syncthreads();

    // ---- pooling: pooled[16][128] packed bf16 hi|lo ----
    #pragma unroll
    for (int rep = 0; rep < 4; ++rep) {
        int idx = rep * 512 + tid;       // < 2048
        int b = idx >> 7, c = idx & 127;
        float p = 0.f;
        #pragma unroll
        for (int o = 0; o < 5; ++o)
            p = fmaf(awb[b * 5 + o], phibuf[(b * 5 + o) * 132 + c], p);
        u16 hi = bf16_rne(p);
        u16 lo = bf16_lo(p, hi);
        poolw[b * 132 + c] = (u32)hi | ((u32)lo << 16);
    }
    __syncthreads();

    // ---- rho: 16x256 = pooled(16x128) @ rhoW(128x256), MFMA, A and B hi/lo ----
    {
        f32x4 acc[2];
        #pragma unroll
        for (int t = 0; t < 2; ++t) acc[t] = (f32x4){0.f, 0.f, 0.f, 0.f};
        #pragma unroll
        for (int c = 0; c < 4; ++c) {
            uint4 q0 = *(const uint4*)(poolw + l15 * 132 + 32 * c + 8 * gq);
            uint4 q1 = *(const uint4*)(poolw + l15 * 132 + 32 * c + 8 * gq + 4);
            u32 ws[8] = {q0.x, q0.y, q0.z, q0.w, q1.x, q1.y, q1.z, q1.w};
            bf16x8 Ah, Al;
            #pragma unroll
            for (int i = 0; i < 8; ++i) {
                Ah[i] = (short)(ws[i] & 0xffffu);
                Al[i] = (short)(ws[i] >> 16);
            }
            #pragma unroll
            for (int t = 0; t < 2; ++t) {
                bf16x8 Bh = *(const bf16x8*)(BpR + (size_t)((c * 16 + 2 * w + t) * 2 + 0) * 512 + lane * 8);
                bf16x8 Bl = *(const bf16x8*)(BpR + (size_t)((c * 16 + 2 * w + t) * 2 + 1) * 512 + lane * 8);
                acc[t] = MFMA16(Ah, Bh, acc[t]);
                acc[t] = MFMA16(Ah, Bl, acc[t]);
                acc[t] = MFMA16(Al, Bh, acc[t]);
            }
        }
        __syncthreads();   // phibuf reads done; safe to overwrite as rbuf
        #pragma unroll
        for (int t = 0; t < 2; ++t) {
            int col = 16 * (2 * w + t) + l15;
            #pragma unroll
            for (int j = 0; j < 4; ++j) {
                int bb = 4 * gq + j;
                float v = fmaxf(acc[t][j] + rhobL[col], 0.f);
                rbuf[bb * 260 + col] = v;
            }
        }
    }
    __syncthreads();

    // ---- heads: out[16][8] = r(16x256) @ headW(256x8) ----
    if (tid < 128) {
        int b = tid >> 3, q = tid & 7;
        float acc = 0.f;
        #pragma unroll 4
        for (int k = 0; k < 256; ++k)
            acc = fmaf(rbuf[b * 260 + k], headW[k * 8 + q], acc);
        int bg = blockIdx.x * 16 + b;
        if (q < 4) {
            outp[(size_t)bg * 4 + q] = acc + meanb[q];
        } else {
            float l = acc + lsb[q - 4];
            outp[65536 + (size_t)bg * 4 + (q - 4)] = fminf(fmaxf(l, -20.0f), 2.0f);
        }
    }
}

extern "C" void kernel_launch(void* const* d_in, const int* in_sizes, int n_in,
                              void* d_out, int out_size, void* d_ws, size_t ws_size,
                              hipStream_t stream)
{
    const float* obs   = (const float*)d_in[0];
    const float* ag    = (const float*)d_in[1];
    const float* g     = (const float*)d_in[2];
    const float* mpW1  = (const float*)d_in[3];
    const float* mpb1  = (const float*)d_in[4];
    const float* mpW2  = (const float*)d_in[5];
    const float* mpb2  = (const float*)d_in[6];
    const float* eaW   = (const float*)d_in[7];
    const float* eab   = (const float*)d_in[8];
    const float* phW1  = (const float*)d_in[9];
    const float* phb1  = (const float*)d_in[10];
    const float* phW2  = (const float*)d_in[11];
    const float* phb2  = (const float*)d_in[12];
    const float* saW   = (const float*)d_in[13];
    const float* sab   = (const float*)d_in[14];
    const float* rhoW  = (const float*)d_in[15];
    const float* rhob  = (const float*)d_in[16];
    const float* meanW = (const float*)d_in[17];
    const float* meanb = (const float*)d_in[18];
    const float* lsW   = (const float*)d_in[19];
    const float* lsb   = (const float*)d_in[20];
    const int*   src   = (const int*)d_in[21];
    const int*   dst   = (const int*)d_in[22];
    const int*   inc   = (const int*)d_in[23];
    const int*   pred  = (const int*)d_in[24];

    // workspace layout (bytes), total ~47.8 MB:
    //  Ein  (u16 327680x32) : [0, 20971520)
    //  Nin  (u16 81920x160) : [20971520, 47185920)
    //  Bp1e (u16 8192)      : [47185920, +16384)
    //  Bp2e (u16 65536)     : [47202304, +131072)
    //  BpC1 (u16 81920)     : [47333376, +163840)
    //  BpC2 (u16 65536)     : [47497216, +131072)
    //  BpR  (u16 65536)     : [47628288, +131072)
    char* ws = (char*)d_ws;
    u16* Ein  = (u16*)(ws + 0);
    u16* Nin  = (u16*)(ws + 20971520ull);
    u16* Bp1e = (u16*)(ws + 47185920ull);
    u16* Bp2e = (u16*)(ws + 47202304ull);
    u16* BpC1 = (u16*)(ws + 47333376ull);
    u16* BpC2 = (u16*)(ws + 47497216ull);
    u16* BpR  = (u16*)(ws + 47628288ull);

    hipLaunchKernelGGL(PK, dim3(1120), dim3(256), 0, stream,
                       mpW1, mpW2, phW1, phW2, rhoW, Bp1e, Bp2e, BpC1, BpC2, BpR);
    hipLaunchKernelGGL(P1, dim3(1280), dim3(256), 0, stream,
                       obs, ag, g, src, dst, pred, Ein);
    hipLaunchKernelGGL(P2, dim3(320), dim3(256), 0, stream, obs, Nin);
    hipLaunchKernelGGL(GA, dim3(4096), dim3(512), 0, stream,
                       Ein, Bp1e, Bp2e, mpb1, mpb2, eaW, eab, inc, Nin);
    hipLaunchKernelGGL(GB, dim3(1024), dim3(512), 0, stream,
                       Nin, BpC1, BpC2, BpR, phb1, phb2, saW, sab, rhob,
                       meanW, meanb, lsW, lsb, (float*)d_out);
}

// Round 4
// 150.188 us; speedup vs baseline: 13.9659x; 1.1149x over previous
//
#include <hip/hip_runtime.h>
#include <cstdint>
#include <cstddef>

typedef unsigned short u16;
typedef unsigned int u32;
typedef __attribute__((ext_vector_type(8))) short bf16x8;
typedef __attribute__((ext_vector_type(4))) float f32x4;

#define MFMA16(A, B, C) __builtin_amdgcn_mfma_f32_16x16x32_bf16((A), (B), (C), 0, 0, 0)

__device__ __forceinline__ u16 bf16_rne(float x) {
    u32 u = __float_as_uint(x);
    u += 0x7fffu + ((u >> 16) & 1u);
    return (u16)(u >> 16);
}
__device__ __forceinline__ float bf2f(u16 h) { return __uint_as_float((u32)h << 16); }
__device__ __forceinline__ u16 bf16_lo(float x, u16 hi) { return bf16_rne(x - bf2f(hi)); }
__device__ __forceinline__ float blo(u32 u) { return __uint_as_float(u << 16); }
__device__ __forceinline__ float bhi(u32 u) { return __uint_as_float(u & 0xffff0000u); }
// packed f32x2 -> bf16x2 (lo<-a, hi<-b), RNE
__device__ __forceinline__ u32 cvt_pk(float a, float b) {
    u32 r;
    asm("v_cvt_pk_bf16_f32 %0, %1, %2" : "=v"(r) : "v"(a), "v"(b));
    return r;
}

// ================= prep bodies =================
// B-frag (16x16x32): lane l, elem i holds B[k = 8*(l>>4)+i][col = 16*tile + (l&15)]
// (identical lane mapping when the same bytes are used as an A-frag: A[row=l&15][k=8*(l>>4)+i])
__device__ __forceinline__ void PK_body(int tid,
    const float* __restrict__ mpW1, const float* __restrict__ mpW2,
    const float* __restrict__ phW1, const float* __restrict__ phW2,
    const float* __restrict__ rhoW,
    u16* __restrict__ Bp1e, u16* __restrict__ Bp2e,
    u16* __restrict__ BpC1, u16* __restrict__ BpC2, u16* __restrict__ BpR)
{
    if (tid < 8192) {
        // edge L1: 16 tiles x 512, 4-group trick [w_hi, w_hi, w_lo, w_lo]
        int t = tid >> 9, r = tid & 511;
        int l = r >> 3, i = r & 7, g = l >> 4, l15 = l & 15;
        float w = mpW1[i * 256 + 16 * t + l15];
        u16 h = bf16_rne(w);
        Bp1e[tid] = (g < 2) ? h : bf16_lo(w, h);
    } else if (tid < 73728) {
        // edge L2: [(c*8+n)*2+s][512] from mpW2 (256x128)
        int f = tid - 8192;
        int b5 = f >> 9, r = f & 511;
        int l = r >> 3, i = r & 7, g = l >> 4, l15 = l & 15;
        int s = b5 & 1, cn = b5 >> 1, c = cn >> 3, n = cn & 7;
        int kk = 32 * c + 8 * g + i;
        float w = mpW2[kk * 128 + 16 * n + l15];
        u16 h = bf16_rne(w);
        Bp2e[f] = s ? bf16_lo(w, h) : h;
    } else if (tid < 155648) {
        // node L1: [(c*2+s)*16+t][512] from phW1 (153x256), K perm: 0..24 direct, 25..31 zero, 32..159 -> 25..152
        int f = tid - 73728;
        int b5 = f >> 9, r = f & 511;
        int l = r >> 3, i = r & 7, g = l >> 4, l15 = l & 15;
        int t = b5 & 15, cs = b5 >> 4, s = cs & 1, c = cs >> 1;
        int kk = 32 * c + 8 * g + i;
        int kp = kk < 25 ? kk : (kk < 32 ? -1 : kk - 7);
        float w = (kp < 0) ? 0.0f : phW1[kp * 256 + 16 * t + l15];
        u16 h = bf16_rne(w);
        BpC1[f] = s ? bf16_lo(w, h) : h;
    } else if (tid < 221184) {
        // node L2: from phW2 (256x128)
        int f = tid - 155648;
        int b5 = f >> 9, r = f & 511;
        int l = r >> 3, i = r & 7, g = l >> 4, l15 = l & 15;
        int s = b5 & 1, cn = b5 >> 1, c = cn >> 3, n = cn & 7;
        int kk = 32 * c + 8 * g + i;
        float w = phW2[kk * 128 + 16 * n + l15];
        u16 h = bf16_rne(w);
        BpC2[f] = s ? bf16_lo(w, h) : h;
    } else {
        // rho: [(c*16+t)*2+s][512] from rhoW (128x256)
        int f = tid - 221184;
        int b5 = f >> 9, r = f & 511;
        int l = r >> 3, i = r & 7, g = l >> 4, l15 = l & 15;
        int s = b5 & 1, ct = b5 >> 1, c = ct >> 4, t = ct & 15;
        int kk = 32 * c + 8 * g + i;
        float w = rhoW[kk * 256 + 16 * t + l15];
        u16 h = bf16_rne(w);
        BpR[f] = s ? bf16_lo(w, h) : h;
    }
}

__device__ __forceinline__ void P1_body(int row,
    const float* __restrict__ obs, const float* __restrict__ ag, const float* __restrict__ g,
    const int* __restrict__ src, const int* __restrict__ dst, const int* __restrict__ pred,
    u16* __restrict__ Ein)
{
    int b = row / 20, p = row - b * 20;
    float inp[8];
    int i0 = pred[2 * p], i1 = pred[2 * p + 1];
    const float* gb = g + (size_t)b * 40;
    const float* ab = ag + (size_t)b * 40;
    inp[0] = gb[i0] - ab[i0];
    inp[1] = gb[i1] - ab[i1];
    int so = src[p], dd = dst[p];
    const float* ob = obs + (size_t)b * 85 + 10;
    inp[2] = ob[so * 15 + 0]; inp[3] = ob[so * 15 + 1]; inp[4] = ob[so * 15 + 2];
    inp[5] = ob[dd * 15 + 0]; inp[6] = ob[dd * 15 + 1]; inp[7] = ob[dd * 15 + 2];

    u32 wh[4], wl[4];
    #pragma unroll
    for (int k = 0; k < 4; ++k) {
        u16 h0 = bf16_rne(inp[2 * k]), h1 = bf16_rne(inp[2 * k + 1]);
        u16 l0 = bf16_lo(inp[2 * k], h0), l1 = bf16_lo(inp[2 * k + 1], h1);
        wh[k] = (u32)h0 | ((u32)h1 << 16);
        wl[k] = (u32)l0 | ((u32)l1 << 16);
    }
    uint4* d4 = (uint4*)(Ein + (size_t)row * 32);
    uint4 vh = make_uint4(wh[0], wh[1], wh[2], wh[3]);
    uint4 vl = make_uint4(wl[0], wl[1], wl[2], wl[3]);
    d4[0] = vh; d4[1] = vl; d4[2] = vh; d4[3] = vl;
}

__device__ __forceinline__ void P2_body(int t, const float* __restrict__ obs, u16* __restrict__ Nin)
{
    int b = t / 5, o = t - b * 5;
    const float* body = obs + (size_t)b * 85;
    const float* op = body + 10 + o * 15;
    u16 v[32];
    #pragma unroll
    for (int k = 0; k < 10; ++k) v[k] = bf16_rne(body[k]);
    #pragma unroll
    for (int k = 0; k < 15; ++k) v[10 + k] = bf16_rne(op[k]);
    #pragma unroll
    for (int k = 25; k < 32; ++k) v[k] = 0;
    u32 wvs[16];
    #pragma unroll
    for (int k = 0; k < 16; ++k) wvs[k] = (u32)v[2 * k] | ((u32)v[2 * k + 1] << 16);
    uint4* d4 = (uint4*)(Nin + (size_t)t * 160);
    d4[0] = make_uint4(wvs[0], wvs[1], wvs[2], wvs[3]);
    d4[1] = make_uint4(wvs[4], wvs[5], wvs[6], wvs[7]);
    d4[2] = make_uint4(wvs[8], wvs[9], wvs[10], wvs[11]);
    d4[3] = make_uint4(wvs[12], wvs[13], wvs[14], wvs[15]);
}

// ================= PREP: PK + P1 + P2 fused =================
__global__ __launch_bounds__(256) void PREP(
    const float* __restrict__ mpW1, const float* __restrict__ mpW2,
    const float* __restrict__ phW1, const float* __restrict__ phW2,
    const float* __restrict__ rhoW,
    u16* __restrict__ Bp1e, u16* __restrict__ Bp2e,
    u16* __restrict__ BpC1, u16* __restrict__ BpC2, u16* __restrict__ BpR,
    const float* __restrict__ obs, const float* __restrict__ ag, const float* __restrict__ g,
    const int* __restrict__ src, const int* __restrict__ dst, const int* __restrict__ pred,
    u16* __restrict__ Ein, u16* __restrict__ Nin)
{
    int bid = blockIdx.x;
    if (bid < 1120) {
        PK_body(bid * 256 + threadIdx.x, mpW1, mpW2, phW1, phW2, rhoW, Bp1e, Bp2e, BpC1, BpC2, BpR);
    } else if (bid < 2400) {
        P1_body((bid - 1120) * 256 + threadIdx.x, obs, ag, g, src, dst, pred, Ein);
    } else {
        P2_body((bid - 2400) * 256 + threadIdx.x, obs, Nin);
    }
}

// ================= GA: fused edge MLP + softmax-aggregate -> Nin[32..159] =================
// 80 rows/block = 4 batches; 512 threads = 8 waves. Operand-swapped MFMAs (C comes out transposed).
__global__ __launch_bounds__(512) void GA(
    const u16* __restrict__ Ein, const u16* __restrict__ Bp1, const u16* __restrict__ Bp2,
    const float* __restrict__ b1, const float* __restrict__ b2,
    const float* __restrict__ eaW, const float* __restrict__ eab,
    const int* __restrict__ inc, u16* __restrict__ Nin)
{
    __shared__ u16 hb[2][16 * 256];     // 16 KB, double-buffered h tile, swizzled
    __shared__ u16 mpb[80 * 128];       // 20 KB, mp values, swizzled
    __shared__ float spart[8][80];      // per-wave e-score partials
    __shared__ float wbuf[80];
    __shared__ int rowb[80];
    __shared__ int incL[20];

    const int tid = threadIdx.x;
    const int w = tid >> 6, lane = tid & 63;
    const int l15 = lane & 15, gq = lane >> 4;
    const int rowbase = blockIdx.x * 80;
    char* hbc = (char*)hb;
    char* mpc = (char*)mpb;

    if (tid < 20) incL[tid] = inc[tid];

    // stage-1 W-frags (tiles 2w, 2w+1) + per-col biases
    bf16x8 B1[2];
    float4 b1v[2];
    #pragma unroll
    for (int t = 0; t < 2; ++t) {
        B1[t] = *(const bf16x8*)(Bp1 + (size_t)(2 * w + t) * 512 + lane * 8);
        b1v[t] = *(const float4*)(b1 + 16 * (2 * w + t) + 4 * gq);
    }
    // stage-2 W-frags (tile n=w), hi/lo + per-col bias/eaW
    bf16x8 B2[8][2];
    #pragma unroll
    for (int c = 0; c < 8; ++c)
        #pragma unroll
        for (int s = 0; s < 2; ++s)
            B2[c][s] = *(const bf16x8*)(Bp2 + (size_t)((c * 8 + w) * 2 + s) * 512 + lane * 8);
    const float4 b2v = *(const float4*)(b2 + 16 * w + 4 * gq);
    const float4 eav = *(const float4*)(eaW + 16 * w + 4 * gq);

    // ---- stage1(m): h[row=l15][col=16t+4gq+j], b64 store ----
    auto stage1 = [&](int m, int buf) {
        const bf16x8 X = *(const bf16x8*)(Ein + (size_t)(rowbase + m * 16 + l15) * 32 + 8 * gq);
        #pragma unroll
        for (int t = 0; t < 2; ++t) {
            f32x4 acc = {b1v[t].x, b1v[t].y, b1v[t].z, b1v[t].w};
            acc = MFMA16(B1[t], X, acc);   // swapped: C[m=col][n=row]
            u32 p0 = cvt_pk(fmaxf(acc[0], 0.f), fmaxf(acc[1], 0.f));
            u32 p1 = cvt_pk(fmaxf(acc[2], 0.f), fmaxf(acc[3], 0.f));
            int colu = 16 * (2 * w + t) + 4 * gq;
            int byte = buf * 8192 + ((l15 * 512 + colu * 2) ^ ((l15 & 7) << 4));
            *(uint2*)(hbc + byte) = make_uint2(p0, p1);
        }
    };
    // ---- stage2(m): mp[row=m*16+l15][col=16w+4gq+j], b64 store + fused e-dot ----
    auto stage2 = [&](int m, int buf) {
        f32x4 acc = {b2v.x, b2v.y, b2v.z, b2v.w};
        #pragma unroll
        for (int c = 0; c < 8; ++c) {
            int byte = buf * 8192 + ((l15 * 512 + c * 64 + gq * 16) ^ ((l15 & 7) << 4));
            const bf16x8 H = *(const bf16x8*)(hbc + byte);
            acc = MFMA16(B2[c][0], H, acc);
            acc = MFMA16(B2[c][1], H, acc);
        }
        float v0 = fmaxf(acc[0], 0.f), v1 = fmaxf(acc[1], 0.f);
        float v2 = fmaxf(acc[2], 0.f), v3 = fmaxf(acc[3], 0.f);
        float ep = v0 * eav.x + v1 * eav.y + v2 * eav.z + v3 * eav.w;
        ep += __shfl_xor(ep, 16, 64);
        ep += __shfl_xor(ep, 32, 64);
        if (gq == 0) spart[w][m * 16 + l15] = ep;
        u32 p0 = cvt_pk(v0, v1), p1 = cvt_pk(v2, v3);
        int r = m * 16 + l15;
        int byte2 = (r * 256 + (16 * w + 4 * gq) * 2) ^ ((r & 15) << 4);
        *(uint2*)(mpc + byte2) = make_uint2(p0, p1);
    };

    stage1(0, 0);
    __syncthreads();
    #pragma unroll 1
    for (int m = 0; m < 5; ++m) {
        if (m < 4) stage1(m + 1, (m + 1) & 1);
        stage2(m, m & 1);
        __syncthreads();
    }

    // ---- softmax weights for 20 (batch,obj) pairs (e-scores from spart) ----
    if (tid < 20) {
        int bl = tid / 5, o = tid - bl * 5;
        const float e0 = eab[0];
        int rr[4]; float ee[4];
        #pragma unroll
        for (int i = 0; i < 4; ++i) {
            rr[i] = bl * 20 + incL[o * 4 + i];
            float e = e0;
            #pragma unroll
            for (int ww = 0; ww < 8; ++ww) e += spart[ww][rr[i]];
            ee[i] = e;
        }
        float mx = fmaxf(fmaxf(ee[0], ee[1]), fmaxf(ee[2], ee[3]));
        float ex[4]; float den = 0.f;
        #pragma unroll
        for (int i = 0; i < 4; ++i) { ex[i] = __expf(ee[i] - mx); den += ex[i]; }
        float inv = 1.0f / den;
        #pragma unroll
        for (int i = 0; i < 4; ++i) {
            wbuf[tid * 4 + i] = ex[i] * inv;
            rowb[tid * 4 + i] = rr[i];
        }
    }
    __syncthreads();

    // ---- weighted gather -> Nin cols 32..159 ----
    if (tid < 320) {
        int p = tid >> 4, cb = tid & 15;
        float acc[8] = {0, 0, 0, 0, 0, 0, 0, 0};
        #pragma unroll
        for (int i = 0; i < 4; ++i) {
            int r = rowb[p * 4 + i];
            float wi = wbuf[p * 4 + i];
            int byte = (r * 256 + cb * 16) ^ ((r & 15) << 4);
            uint4 v = *(const uint4*)(mpc + byte);
            acc[0] = fmaf(wi, blo(v.x), acc[0]);
            acc[1] = fmaf(wi, bhi(v.x), acc[1]);
            acc[2] = fmaf(wi, blo(v.y), acc[2]);
            acc[3] = fmaf(wi, bhi(v.y), acc[3]);
            acc[4] = fmaf(wi, blo(v.z), acc[4]);
            acc[5] = fmaf(wi, bhi(v.z), acc[5]);
            acc[6] = fmaf(wi, blo(v.w), acc[6]);
            acc[7] = fmaf(wi, bhi(v.w), acc[7]);
        }
        uint4 ov;
        ov.x = cvt_pk(acc[0], acc[1]);
        ov.y = cvt_pk(acc[2], acc[3]);
        ov.z = cvt_pk(acc[4], acc[5]);
        ov.w = cvt_pk(acc[6], acc[7]);
        int grow = blockIdx.x * 20 + p;
        *(uint4*)(Nin + (size_t)grow * 160 + 32 + cb * 8) = ov;
    }
}

// ================= GB: fused node MLP + attn-pool + rho + heads -> out =================
// 80 rows/block = 16 batches; 512 threads = 8 waves. Operand-swapped MFMAs.
__global__ __launch_bounds__(512) void GB(
    const u16* __restrict__ Nin, const u16* __restrict__ BpC1, const u16* __restrict__ BpC2,
    const u16* __restrict__ BpR,
    const float* __restrict__ b1, const float* __restrict__ b2,
    const float* __restrict__ saW, const float* __restrict__ sab,
    const float* __restrict__ rhob,
    const float* __restrict__ meanW, const float* __restrict__ meanb,
    const float* __restrict__ lsW, const float* __restrict__ lsb,
    float* __restrict__ outp)
{
    __shared__ u16 hb[2][16 * 256];      // 16 KB
    __shared__ float phibuf[80 * 132];   // 42.25 KB padded; later aliased as rbuf[16][260]
    __shared__ u32 poolw[16 * 132];      // packed hi|lo bf16
    __shared__ float spart[8][80];
    __shared__ float awb[80];
    __shared__ float headW[2048];        // [k][q]: q<4 mean, q>=4 logstd

    const int tid = threadIdx.x;
    const int w = tid >> 6, lane = tid & 63;
    const int l15 = lane & 15, gq = lane >> 4;
    const int rowbase = blockIdx.x * 80;
    char* hbc = (char*)hb;
    float* rbuf = phibuf;                // alias, stride 260 f32

    #pragma unroll
    for (int idx = tid; idx < 2048; idx += 512) {
        int k = idx >> 3, q = idx & 7;
        headW[idx] = (q < 4) ? meanW[k * 4 + q] : lsW[k * 4 + (q - 4)];
    }

    // stage-1 W-frags: 5 chunks x {hi,lo} x 2 tiles + per-col bias
    bf16x8 BC[5][2][2];
    float4 b1v[2];
    #pragma unroll
    for (int t = 0; t < 2; ++t) b1v[t] = *(const float4*)(b1 + 16 * (2 * w + t) + 4 * gq);
    #pragma unroll
    for (int c = 0; c < 5; ++c)
        #pragma unroll
        for (int s = 0; s < 2; ++s)
            #pragma unroll
            for (int t = 0; t < 2; ++t)
                BC[c][s][t] = *(const bf16x8*)(BpC1 + (size_t)((c * 2 + s) * 16 + 2 * w + t) * 512 + lane * 8);
    // stage-2 W-frags + per-col bias/saW
    bf16x8 B2[8][2];
    #pragma unroll
    for (int c = 0; c < 8; ++c)
        #pragma unroll
        for (int s = 0; s < 2; ++s)
            B2[c][s] = *(const bf16x8*)(BpC2 + (size_t)((c * 8 + w) * 2 + s) * 512 + lane * 8);
    const float4 b2v = *(const float4*)(b2 + 16 * w + 4 * gq);
    const float4 sav = *(const float4*)(saW + 16 * w + 4 * gq);

    auto stage1 = [&](int m, int buf) {
        f32x4 a0 = {b1v[0].x, b1v[0].y, b1v[0].z, b1v[0].w};
        f32x4 a1 = {b1v[1].x, b1v[1].y, b1v[1].z, b1v[1].w};
        #pragma unroll
        for (int c = 0; c < 5; ++c) {
            const bf16x8 X = *(const bf16x8*)(Nin + (size_t)(rowbase + m * 16 + l15) * 160 + 32 * c + 8 * gq);
            a0 = MFMA16(BC[c][0][0], X, a0);
            a0 = MFMA16(BC[c][1][0], X, a0);
            a1 = MFMA16(BC[c][0][1], X, a1);
            a1 = MFMA16(BC[c][1][1], X, a1);
        }
        #pragma unroll
        for (int t = 0; t < 2; ++t) {
            const f32x4& a = t ? a1 : a0;
            u32 p0 = cvt_pk(fmaxf(a[0], 0.f), fmaxf(a[1], 0.f));
            u32 p1 = cvt_pk(fmaxf(a[2], 0.f), fmaxf(a[3], 0.f));
            int colu = 16 * (2 * w + t) + 4 * gq;
            int byte = buf * 8192 + ((l15 * 512 + colu * 2) ^ ((l15 & 7) << 4));
            *(uint2*)(hbc + byte) = make_uint2(p0, p1);
        }
    };
    auto stage2 = [&](int m, int buf) {
        f32x4 acc = {b2v.x, b2v.y, b2v.z, b2v.w};
        #pragma unroll
        for (int c = 0; c < 8; ++c) {
            int byte = buf * 8192 + ((l15 * 512 + c * 64 + gq * 16) ^ ((l15 & 7) << 4));
            const bf16x8 H = *(const bf16x8*)(hbc + byte);
            acc = MFMA16(B2[c][0], H, acc);
            acc = MFMA16(B2[c][1], H, acc);
        }
        float4 v;
        v.x = fmaxf(acc[0], 0.f); v.y = fmaxf(acc[1], 0.f);
        v.z = fmaxf(acc[2], 0.f); v.w = fmaxf(acc[3], 0.f);
        int r = m * 16 + l15;
        *(float4*)(phibuf + r * 132 + 16 * w + 4 * gq) = v;
        float sp = v.x * sav.x + v.y * sav.y + v.z * sav.z + v.w * sav.w;
        sp += __shfl_xor(sp, 16, 64);
        sp += __shfl_xor(sp, 32, 64);
        if (gq == 0) spart[w][r] = sp;
    };

    stage1(0, 0);
    __syncthreads();
    #pragma unroll 1
    for (int m = 0; m < 5; ++m) {
        if (m < 4) stage1(m + 1, (m + 1) & 1);
        stage2(m, m & 1);
        __syncthreads();
    }

    // ---- softmax over 5 objects per batch (scores from spart) ----
    if (tid < 16) {
        const float s0c = sab[0];
        float ss[5];
        #pragma unroll
        for (int o = 0; o < 5; ++o) {
            float s = s0c;
            #pragma unroll
            for (int ww = 0; ww < 8; ++ww) s += spart[ww][tid * 5 + o];
            ss[o] = s;
        }
        float mx = fmaxf(fmaxf(fmaxf(ss[0], ss[1]), fmaxf(ss[2], ss[3])), ss[4]);
        float ex[5]; float den = 0.f;
        #pragma unroll
        for (int o = 0; o < 5; ++o) { ex[o] = __expf(ss[o] - mx); den += ex[o]; }
        float inv = 1.0f / den;
        #pragma unroll
        for (int o = 0; o < 5; ++o) awb[tid * 5 + o] = ex[o] * inv;
    }
    __syncthreads();

    // ---- pooling: pooled[16][128] packed bf16 hi|lo ----
    #pragma unroll
    for (int rep = 0; rep < 4; ++rep) {
        int idx = rep * 512 + tid;       // < 2048
        int b = idx >> 7, c = idx & 127;
        float p = 0.f;
        #pragma unroll
        for (int o = 0; o < 5; ++o)
            p = fmaf(awb[b * 5 + o], phibuf[(b * 5 + o) * 132 + c], p);
        u16 hi = bf16_rne(p);
        u16 lo = bf16_lo(p, hi);
        poolw[b * 132 + c] = (u32)hi | ((u32)lo << 16);
    }
    __syncthreads();

    // ---- rho (swapped): r[row=l15][col=16(2w+t)+4gq+j] ----
    {
        float4 rb0 = *(const float4*)(rhob + 16 * (2 * w + 0) + 4 * gq);
        float4 rb1 = *(const float4*)(rhob + 16 * (2 * w + 1) + 4 * gq);
        f32x4 acc0 = {rb0.x, rb0.y, rb0.z, rb0.w};
        f32x4 acc1 = {rb1.x, rb1.y, rb1.z, rb1.w};
        #pragma unroll
        for (int c = 0; c < 4; ++c) {
            uint4 q0 = *(const uint4*)(poolw + l15 * 132 + 32 * c + 8 * gq);
            uint4 q1 = *(const uint4*)(poolw + l15 * 132 + 32 * c + 8 * gq + 4);
            u32 ws[8] = {q0.x, q0.y, q0.z, q0.w, q1.x, q1.y, q1.z, q1.w};
            bf16x8 Ph, Pl;
            #pragma unroll
            for (int i = 0; i < 8; ++i) {
                Ph[i] = (short)(ws[i] & 0xffffu);
                Pl[i] = (short)(ws[i] >> 16);
            }
            #pragma unroll
            for (int t = 0; t < 2; ++t) {
                bf16x8 Bh = *(const bf16x8*)(BpR + (size_t)((c * 16 + 2 * w + t) * 2 + 0) * 512 + lane * 8);
                bf16x8 Bl = *(const bf16x8*)(BpR + (size_t)((c * 16 + 2 * w + t) * 2 + 1) * 512 + lane * 8);
                f32x4& a = t ? acc1 : acc0;
                a = MFMA16(Bh, Ph, a);
                a = MFMA16(Bl, Ph, a);
                a = MFMA16(Bh, Pl, a);
            }
        }
        #pragma unroll
        for (int t = 0; t < 2; ++t) {
            const f32x4& a = t ? acc1 : acc0;
            float4 v;
            v.x = fmaxf(a[0], 0.f); v.y = fmaxf(a[1], 0.f);
            v.z = fmaxf(a[2], 0.f); v.w = fmaxf(a[3], 0.f);
            *(float4*)(rbuf + l15 * 260 + 16 * (2 * w + t) + 4 * gq) = v;
        }
    }
    __syncthreads();

    // ---- heads: out[16][8] = r(16x256) @ headW(256x8) ----
    if (tid < 128) {
        int b = tid >> 3, q = tid & 7;
        float acc = 0.f;
        #pragma unroll 4
        for (int k = 0; k < 256; ++k)
            acc = fmaf(rbuf[b * 260 + k], headW[k * 8 + q], acc);
        int bg = blockIdx.x * 16 + b;
        if (q < 4) {
            outp[(size_t)bg * 4 + q] = acc + meanb[q];
        } else {
            float l = acc + lsb[q - 4];
            outp[65536 + (size_t)bg * 4 + (q - 4)] = fminf(fmaxf(l, -20.0f), 2.0f);
        }
    }
}

extern "C" void kernel_launch(void* const* d_in, const int* in_sizes, int n_in,
                              void* d_out, int out_size, void* d_ws, size_t ws_size,
                              hipStream_t stream)
{
    const float* obs   = (const float*)d_in[0];
    const float* ag    = (const float*)d_in[1];
    const float* g     = (const float*)d_in[2];
    const float* mpW1  = (const float*)d_in[3];
    const float* mpb1  = (const float*)d_in[4];
    const float* mpW2  = (const float*)d_in[5];
    const float* mpb2  = (const float*)d_in[6];
    const float* eaW   = (const float*)d_in[7];
    const float* eab   = (const float*)d_in[8];
    const float* phW1  = (const float*)d_in[9];
    const float* phb1  = (const float*)d_in[10];
    const float* phW2  = (const float*)d_in[11];
    const float* phb2  = (const float*)d_in[12];
    const float* saW   = (const float*)d_in[13];
    const float* sab   = (const float*)d_in[14];
    const float* rhoW  = (const float*)d_in[15];
    const float* rhob  = (const float*)d_in[16];
    const float* meanW = (const float*)d_in[17];
    const float* meanb = (const float*)d_in[18];
    const float* lsW   = (const float*)d_in[19];
    const float* lsb   = (const float*)d_in[20];
    const int*   src   = (const int*)d_in[21];
    const int*   dst   = (const int*)d_in[22];
    const int*   inc   = (const int*)d_in[23];
    const int*   pred  = (const int*)d_in[24];

    // workspace layout (bytes), total ~47.8 MB:
    //  Ein  (u16 327680x32) : [0, 20971520)
    //  Nin  (u16 81920x160) : [20971520, 47185920)
    //  Bp1e (u16 8192)      : [47185920, +16384)
    //  Bp2e (u16 65536)     : [47202304, +131072)
    //  BpC1 (u16 81920)     : [47333376, +163840)
    //  BpC2 (u16 65536)     : [47497216, +131072)
    //  BpR  (u16 65536)     : [47628288, +131072)
    char* ws = (char*)d_ws;
    u16* Ein  = (u16*)(ws + 0);
    u16* Nin  = (u16*)(ws + 20971520ull);
    u16* Bp1e = (u16*)(ws + 47185920ull);
    u16* Bp2e = (u16*)(ws + 47202304ull);
    u16* BpC1 = (u16*)(ws + 47333376ull);
    u16* BpC2 = (u16*)(ws + 47497216ull);
    u16* BpR  = (u16*)(ws + 47628288ull);

    hipLaunchKernelGGL(PREP, dim3(2720), dim3(256), 0, stream,
                       mpW1, mpW2, phW1, phW2, rhoW, Bp1e, Bp2e, BpC1, BpC2, BpR,
                       obs, ag, g, src, dst, pred, Ein, Nin);
    hipLaunchKernelGGL(GA, dim3(4096), dim3(512), 0, stream,
                       Ein, Bp1e, Bp2e, mpb1, mpb2, eaW, eab, inc, Nin);
    hipLaunchKernelGGL(GB, dim3(1024), dim3(512), 0, stream,
                       Nin, BpC1, BpC2, BpR, phb1, phb2, saW, sab, rhob,
                       meanW, meanb, lsW, lsb, (float*)d_out);
}

// Round 5
// 127.820 us; speedup vs baseline: 16.4099x; 1.1750x over previous
//
#include <hip/hip_runtime.h>
#include <cstdint>
#include <cstddef>

typedef unsigned short u16;
typedef unsigned int u32;
typedef __attribute__((ext_vector_type(8))) short bf16x8;
typedef __attribute__((ext_vector_type(4))) float f32x4;

#define MFMA16(A, B, C) __builtin_amdgcn_mfma_f32_16x16x32_bf16((A), (B), (C), 0, 0, 0)

__device__ __forceinline__ u16 bf16_rne(float x) {
    u32 u = __float_as_uint(x);
    u += 0x7fffu + ((u >> 16) & 1u);
    return (u16)(u >> 16);
}
__device__ __forceinline__ float bf2f(u16 h) { return __uint_as_float((u32)h << 16); }
__device__ __forceinline__ u16 bf16_lo(float x, u16 hi) { return bf16_rne(x - bf2f(hi)); }
__device__ __forceinline__ float blo(u32 u) { return __uint_as_float(u << 16); }
__device__ __forceinline__ float bhi(u32 u) { return __uint_as_float(u & 0xffff0000u); }
// packed f32x2 -> bf16x2 (lo<-a, hi<-b), RNE
__device__ __forceinline__ u32 cvt_pk(float a, float b) {
    u32 r;
    asm("v_cvt_pk_bf16_f32 %0, %1, %2" : "=v"(r) : "v"(a), "v"(b));
    return r;
}

// ================= prep bodies =================
// B-frag (16x16x32): lane l, elem i holds B[k = 8*(l>>4)+i][col = 16*tile + (l&15)]
// (same bytes as A-frag give A[row=l&15][k=8*(l>>4)+i] -> operand-swap transposes C)
__device__ __forceinline__ void PK_body(int tid,
    const float* __restrict__ mpW1, const float* __restrict__ mpW2,
    const float* __restrict__ phW1, const float* __restrict__ phW2,
    const float* __restrict__ rhoW,
    u16* __restrict__ Bp1e, u16* __restrict__ Bp2e,
    u16* __restrict__ BpC1, u16* __restrict__ BpC2, u16* __restrict__ BpR)
{
    if (tid < 8192) {
        // edge L1: 16 tiles x 512, 4-group trick [w_hi, w_hi, w_lo, w_lo]
        int t = tid >> 9, r = tid & 511;
        int l = r >> 3, i = r & 7, g = l >> 4, l15 = l & 15;
        float w = mpW1[i * 256 + 16 * t + l15];
        u16 h = bf16_rne(w);
        Bp1e[tid] = (g < 2) ? h : bf16_lo(w, h);
    } else if (tid < 73728) {
        // edge L2: [(c*8+n)*2+s][512] from mpW2 (256x128)
        int f = tid - 8192;
        int b5 = f >> 9, r = f & 511;
        int l = r >> 3, i = r & 7, g = l >> 4, l15 = l & 15;
        int s = b5 & 1, cn = b5 >> 1, c = cn >> 3, n = cn & 7;
        int kk = 32 * c + 8 * g + i;
        float w = mpW2[kk * 128 + 16 * n + l15];
        u16 h = bf16_rne(w);
        Bp2e[f] = s ? bf16_lo(w, h) : h;
    } else if (tid < 155648) {
        // node L1: [(c*2+s)*16+t][512] from phW1 (153x256), K perm: 0..24 direct, 25..31 zero, 32..159 -> 25..152
        int f = tid - 73728;
        int b5 = f >> 9, r = f & 511;
        int l = r >> 3, i = r & 7, g = l >> 4, l15 = l & 15;
        int t = b5 & 15, cs = b5 >> 4, s = cs & 1, c = cs >> 1;
        int kk = 32 * c + 8 * g + i;
        int kp = kk < 25 ? kk : (kk < 32 ? -1 : kk - 7);
        float w = (kp < 0) ? 0.0f : phW1[kp * 256 + 16 * t + l15];
        u16 h = bf16_rne(w);
        BpC1[f] = s ? bf16_lo(w, h) : h;
    } else if (tid < 221184) {
        // node L2: from phW2 (256x128)
        int f = tid - 155648;
        int b5 = f >> 9, r = f & 511;
        int l = r >> 3, i = r & 7, g = l >> 4, l15 = l & 15;
        int s = b5 & 1, cn = b5 >> 1, c = cn >> 3, n = cn & 7;
        int kk = 32 * c + 8 * g + i;
        float w = phW2[kk * 128 + 16 * n + l15];
        u16 h = bf16_rne(w);
        BpC2[f] = s ? bf16_lo(w, h) : h;
    } else {
        // rho: [(c*16+t)*2+s][512] from rhoW (128x256)
        int f = tid - 221184;
        int b5 = f >> 9, r = f & 511;
        int l = r >> 3, i = r & 7, g = l >> 4, l15 = l & 15;
        int s = b5 & 1, ct = b5 >> 1, c = ct >> 4, t = ct & 15;
        int kk = 32 * c + 8 * g + i;
        float w = rhoW[kk * 256 + 16 * t + l15];
        u16 h = bf16_rne(w);
        BpR[f] = s ? bf16_lo(w, h) : h;
    }
}

__device__ __forceinline__ void P1_body(int row,
    const float* __restrict__ obs, const float* __restrict__ ag, const float* __restrict__ g,
    const int* __restrict__ src, const int* __restrict__ dst, const int* __restrict__ pred,
    u16* __restrict__ Ein)
{
    int b = row / 20, p = row - b * 20;
    float inp[8];
    int i0 = pred[2 * p], i1 = pred[2 * p + 1];
    const float* gb = g + (size_t)b * 40;
    const float* ab = ag + (size_t)b * 40;
    inp[0] = gb[i0] - ab[i0];
    inp[1] = gb[i1] - ab[i1];
    int so = src[p], dd = dst[p];
    const float* ob = obs + (size_t)b * 85 + 10;
    inp[2] = ob[so * 15 + 0]; inp[3] = ob[so * 15 + 1]; inp[4] = ob[so * 15 + 2];
    inp[5] = ob[dd * 15 + 0]; inp[6] = ob[dd * 15 + 1]; inp[7] = ob[dd * 15 + 2];

    u32 wh[4], wl[4];
    #pragma unroll
    for (int k = 0; k < 4; ++k) {
        u16 h0 = bf16_rne(inp[2 * k]), h1 = bf16_rne(inp[2 * k + 1]);
        u16 l0 = bf16_lo(inp[2 * k], h0), l1 = bf16_lo(inp[2 * k + 1], h1);
        wh[k] = (u32)h0 | ((u32)h1 << 16);
        wl[k] = (u32)l0 | ((u32)l1 << 16);
    }
    uint4* d4 = (uint4*)(Ein + (size_t)row * 32);
    uint4 vh = make_uint4(wh[0], wh[1], wh[2], wh[3]);
    uint4 vl = make_uint4(wl[0], wl[1], wl[2], wl[3]);
    d4[0] = vh; d4[1] = vl; d4[2] = vh; d4[3] = vl;
}

__device__ __forceinline__ void P2_body(int t, const float* __restrict__ obs, u16* __restrict__ Nin)
{
    int b = t / 5, o = t - b * 5;
    const float* body = obs + (size_t)b * 85;
    const float* op = body + 10 + o * 15;
    u16 v[32];
    #pragma unroll
    for (int k = 0; k < 10; ++k) v[k] = bf16_rne(body[k]);
    #pragma unroll
    for (int k = 0; k < 15; ++k) v[10 + k] = bf16_rne(op[k]);
    #pragma unroll
    for (int k = 25; k < 32; ++k) v[k] = 0;
    u32 wvs[16];
    #pragma unroll
    for (int k = 0; k < 16; ++k) wvs[k] = (u32)v[2 * k] | ((u32)v[2 * k + 1] << 16);
    uint4* d4 = (uint4*)(Nin + (size_t)t * 160);
    d4[0] = make_uint4(wvs[0], wvs[1], wvs[2], wvs[3]);
    d4[1] = make_uint4(wvs[4], wvs[5], wvs[6], wvs[7]);
    d4[2] = make_uint4(wvs[8], wvs[9], wvs[10], wvs[11]);
    d4[3] = make_uint4(wvs[12], wvs[13], wvs[14], wvs[15]);
}

// ================= PREP: PK + P1 + P2 fused =================
__global__ __launch_bounds__(256) void PREP(
    const float* __restrict__ mpW1, const float* __restrict__ mpW2,
    const float* __restrict__ phW1, const float* __restrict__ phW2,
    const float* __restrict__ rhoW,
    u16* __restrict__ Bp1e, u16* __restrict__ Bp2e,
    u16* __restrict__ BpC1, u16* __restrict__ BpC2, u16* __restrict__ BpR,
    const float* __restrict__ obs, const float* __restrict__ ag, const float* __restrict__ g,
    const int* __restrict__ src, const int* __restrict__ dst, const int* __restrict__ pred,
    u16* __restrict__ Ein, u16* __restrict__ Nin)
{
    int bid = blockIdx.x;
    if (bid < 1120) {
        PK_body(bid * 256 + threadIdx.x, mpW1, mpW2, phW1, phW2, rhoW, Bp1e, Bp2e, BpC1, BpC2, BpR);
    } else if (bid < 2400) {
        P1_body((bid - 1120) * 256 + threadIdx.x, obs, ag, g, src, dst, pred, Ein);
    } else {
        P2_body((bid - 2400) * 256 + threadIdx.x, obs, Nin);
    }
}

// ================= GA: fused edge MLP + softmax-aggregate -> Nin[32..159] =================
// 80 rows/block = 4 batches; 512 threads = 8 waves. Operand-swapped MFMAs, hi-only L2 weights.
__global__ __launch_bounds__(512) void GA(
    const u16* __restrict__ Ein, const u16* __restrict__ Bp1, const u16* __restrict__ Bp2,
    const float* __restrict__ b1, const float* __restrict__ b2,
    const float* __restrict__ eaW, const float* __restrict__ eab,
    const int* __restrict__ inc, u16* __restrict__ Nin)
{
    __shared__ u16 hb[2][16 * 256];     // 16 KB, double-buffered h tile, swizzled
    __shared__ u16 mpb[80 * 128];       // 20 KB, mp values, swizzled
    __shared__ float spart[8][80];      // per-wave e-score partials
    __shared__ float wbuf[80];
    __shared__ int rowb[80];
    __shared__ int incL[20];

    const int tid = threadIdx.x;
    const int w = tid >> 6, lane = tid & 63;
    const int l15 = lane & 15, gq = lane >> 4;
    const int rowbase = blockIdx.x * 80;
    char* hbc = (char*)hb;
    char* mpc = (char*)mpb;

    if (tid < 20) incL[tid] = inc[tid];

    // stage-1 W-frags (tiles 2w, 2w+1; exact 4-group hi/lo) + per-col biases
    bf16x8 B1[2];
    float4 b1v[2];
    #pragma unroll
    for (int t = 0; t < 2; ++t) {
        B1[t] = *(const bf16x8*)(Bp1 + (size_t)(2 * w + t) * 512 + lane * 8);
        b1v[t] = *(const float4*)(b1 + 16 * (2 * w + t) + 4 * gq);
    }
    // stage-2 W-frags (tile n=w), hi only
    bf16x8 B2[8];
    #pragma unroll
    for (int c = 0; c < 8; ++c)
        B2[c] = *(const bf16x8*)(Bp2 + (size_t)((c * 8 + w) * 2) * 512 + lane * 8);
    const float4 b2v = *(const float4*)(b2 + 16 * w + 4 * gq);
    const float4 eav = *(const float4*)(eaW + 16 * w + 4 * gq);

    // ---- stage1(m): h[row=l15][col=16t+4gq+j], b64 store ----
    auto stage1 = [&](int buf, const bf16x8& X) {
        #pragma unroll
        for (int t = 0; t < 2; ++t) {
            f32x4 acc = {b1v[t].x, b1v[t].y, b1v[t].z, b1v[t].w};
            acc = MFMA16(B1[t], X, acc);   // swapped: C[m=col][n=row]
            u32 p0 = cvt_pk(fmaxf(acc[0], 0.f), fmaxf(acc[1], 0.f));
            u32 p1 = cvt_pk(fmaxf(acc[2], 0.f), fmaxf(acc[3], 0.f));
            int colu = 16 * (2 * w + t) + 4 * gq;
            int byte = buf * 8192 + ((l15 * 512 + colu * 2) ^ ((l15 & 7) << 4));
            *(uint2*)(hbc + byte) = make_uint2(p0, p1);
        }
    };
    // ---- stage2(m): two indep acc chains; mp write + fused e-dot ----
    auto stage2 = [&](int m, int buf) {
        f32x4 accA = {b2v.x, b2v.y, b2v.z, b2v.w};
        f32x4 accB = {0.f, 0.f, 0.f, 0.f};
        #pragma unroll
        for (int c = 0; c < 4; ++c) {
            int byteA = buf * 8192 + ((l15 * 512 + (2 * c) * 64 + gq * 16) ^ ((l15 & 7) << 4));
            int byteB = buf * 8192 + ((l15 * 512 + (2 * c + 1) * 64 + gq * 16) ^ ((l15 & 7) << 4));
            const bf16x8 HA = *(const bf16x8*)(hbc + byteA);
            const bf16x8 HB = *(const bf16x8*)(hbc + byteB);
            accA = MFMA16(B2[2 * c], HA, accA);
            accB = MFMA16(B2[2 * c + 1], HB, accB);
        }
        float v0 = fmaxf(accA[0] + accB[0], 0.f), v1 = fmaxf(accA[1] + accB[1], 0.f);
        float v2 = fmaxf(accA[2] + accB[2], 0.f), v3 = fmaxf(accA[3] + accB[3], 0.f);
        float ep = v0 * eav.x + v1 * eav.y + v2 * eav.z + v3 * eav.w;
        ep += __shfl_xor(ep, 16, 64);
        ep += __shfl_xor(ep, 32, 64);
        if (gq == 0) spart[w][m * 16 + l15] = ep;
        u32 p0 = cvt_pk(v0, v1), p1 = cvt_pk(v2, v3);
        int r = m * 16 + l15;
        int byte2 = (r * 256 + (16 * w + 4 * gq) * 2) ^ ((r & 15) << 4);
        *(uint2*)(mpc + byte2) = make_uint2(p0, p1);
    };

    bf16x8 Xc = *(const bf16x8*)(Ein + (size_t)(rowbase + l15) * 32 + 8 * gq);
    stage1(0, Xc);
    __syncthreads();
    #pragma unroll 1
    for (int m = 0; m < 5; ++m) {
        bf16x8 Xn;
        if (m < 4)   // issue global load early; stage2's LDS+MFMA work hides it
            Xn = *(const bf16x8*)(Ein + (size_t)(rowbase + (m + 1) * 16 + l15) * 32 + 8 * gq);
        stage2(m, m & 1);
        if (m < 4) stage1((m + 1) & 1, Xn);
        __syncthreads();
    }

    // ---- softmax weights for 20 (batch,obj) pairs ----
    if (tid < 20) {
        int bl = tid / 5, o = tid - bl * 5;
        const float e0 = eab[0];
        int rr[4]; float ee[4];
        #pragma unroll
        for (int i = 0; i < 4; ++i) {
            rr[i] = bl * 20 + incL[o * 4 + i];
            float e = e0;
            #pragma unroll
            for (int ww = 0; ww < 8; ++ww) e += spart[ww][rr[i]];
            ee[i] = e;
        }
        float mx = fmaxf(fmaxf(ee[0], ee[1]), fmaxf(ee[2], ee[3]));
        float ex[4]; float den = 0.f;
        #pragma unroll
        for (int i = 0; i < 4; ++i) { ex[i] = __expf(ee[i] - mx); den += ex[i]; }
        float inv = 1.0f / den;
        #pragma unroll
        for (int i = 0; i < 4; ++i) {
            wbuf[tid * 4 + i] = ex[i] * inv;
            rowb[tid * 4 + i] = rr[i];
        }
    }
    __syncthreads();

    // ---- weighted gather -> Nin cols 32..159 ----
    if (tid < 320) {
        int p = tid >> 4, cb = tid & 15;
        float acc[8] = {0, 0, 0, 0, 0, 0, 0, 0};
        #pragma unroll
        for (int i = 0; i < 4; ++i) {
            int r = rowb[p * 4 + i];
            float wi = wbuf[p * 4 + i];
            int byte = (r * 256 + cb * 16) ^ ((r & 15) << 4);
            uint4 v = *(const uint4*)(mpc + byte);
            acc[0] = fmaf(wi, blo(v.x), acc[0]);
            acc[1] = fmaf(wi, bhi(v.x), acc[1]);
            acc[2] = fmaf(wi, blo(v.y), acc[2]);
            acc[3] = fmaf(wi, bhi(v.y), acc[3]);
            acc[4] = fmaf(wi, blo(v.z), acc[4]);
            acc[5] = fmaf(wi, bhi(v.z), acc[5]);
            acc[6] = fmaf(wi, blo(v.w), acc[6]);
            acc[7] = fmaf(wi, bhi(v.w), acc[7]);
        }
        uint4 ov;
        ov.x = cvt_pk(acc[0], acc[1]);
        ov.y = cvt_pk(acc[2], acc[3]);
        ov.z = cvt_pk(acc[4], acc[5]);
        ov.w = cvt_pk(acc[6], acc[7]);
        int grow = blockIdx.x * 20 + p;
        *(uint4*)(Nin + (size_t)grow * 160 + 32 + cb * 8) = ov;
    }
}

// ================= GB: fused node MLP + attn-pool + rho + heads -> out =================
// 80 rows/block = 16 batches; 512 threads = 8 waves. Hi-only weights in L1/L2/rho-B.
__global__ __launch_bounds__(512) void GB(
    const u16* __restrict__ Nin, const u16* __restrict__ BpC1, const u16* __restrict__ BpC2,
    const u16* __restrict__ BpR,
    const float* __restrict__ b1, const float* __restrict__ b2,
    const float* __restrict__ saW, const float* __restrict__ sab,
    const float* __restrict__ rhob,
    const float* __restrict__ meanW, const float* __restrict__ meanb,
    const float* __restrict__ lsW, const float* __restrict__ lsb,
    float* __restrict__ outp)
{
    __shared__ u16 hb[2][16 * 256];      // 16 KB
    __shared__ float phibuf[80 * 132];   // 42.25 KB padded; later aliased as rbuf[16][260]
    __shared__ u32 poolw[16 * 132];      // packed hi|lo bf16
    __shared__ float spart[8][80];
    __shared__ float awb[80];
    __shared__ float headW[2048];        // [k][q]: q<4 mean, q>=4 logstd

    const int tid = threadIdx.x;
    const int w = tid >> 6, lane = tid & 63;
    const int l15 = lane & 15, gq = lane >> 4;
    const int rowbase = blockIdx.x * 80;
    char* hbc = (char*)hb;
    float* rbuf = phibuf;                // alias, stride 260 f32

    #pragma unroll
    for (int idx = tid; idx < 2048; idx += 512) {
        int k = idx >> 3, q = idx & 7;
        headW[idx] = (q < 4) ? meanW[k * 4 + q] : lsW[k * 4 + (q - 4)];
    }

    // stage-1 W-frags: 5 chunks x 2 tiles, hi only + per-col bias
    bf16x8 BC[5][2];
    float4 b1v[2];
    #pragma unroll
    for (int t = 0; t < 2; ++t) b1v[t] = *(const float4*)(b1 + 16 * (2 * w + t) + 4 * gq);
    #pragma unroll
    for (int c = 0; c < 5; ++c)
        #pragma unroll
        for (int t = 0; t < 2; ++t)
            BC[c][t] = *(const bf16x8*)(BpC1 + (size_t)((c * 2) * 16 + 2 * w + t) * 512 + lane * 8);
    // stage-2 W-frags, hi only
    bf16x8 B2[8];
    #pragma unroll
    for (int c = 0; c < 8; ++c)
        B2[c] = *(const bf16x8*)(BpC2 + (size_t)((c * 8 + w) * 2) * 512 + lane * 8);
    const float4 b2v = *(const float4*)(b2 + 16 * w + 4 * gq);
    const float4 sav = *(const float4*)(saW + 16 * w + 4 * gq);

    auto loadX = [&](int m, bf16x8* X) {
        #pragma unroll
        for (int c = 0; c < 5; ++c)
            X[c] = *(const bf16x8*)(Nin + (size_t)(rowbase + m * 16 + l15) * 160 + 32 * c + 8 * gq);
    };
    auto stage1 = [&](int buf, const bf16x8* X) {
        f32x4 a0 = {b1v[0].x, b1v[0].y, b1v[0].z, b1v[0].w};
        f32x4 a1 = {b1v[1].x, b1v[1].y, b1v[1].z, b1v[1].w};
        #pragma unroll
        for (int c = 0; c < 5; ++c) {
            a0 = MFMA16(BC[c][0], X[c], a0);
            a1 = MFMA16(BC[c][1], X[c], a1);
        }
        #pragma unroll
        for (int t = 0; t < 2; ++t) {
            const f32x4& a = t ? a1 : a0;
            u32 p0 = cvt_pk(fmaxf(a[0], 0.f), fmaxf(a[1], 0.f));
            u32 p1 = cvt_pk(fmaxf(a[2], 0.f), fmaxf(a[3], 0.f));
            int colu = 16 * (2 * w + t) + 4 * gq;
            int byte = buf * 8192 + ((l15 * 512 + colu * 2) ^ ((l15 & 7) << 4));
            *(uint2*)(hbc + byte) = make_uint2(p0, p1);
        }
    };
    auto stage2 = [&](int m, int buf) {
        f32x4 accA = {b2v.x, b2v.y, b2v.z, b2v.w};
        f32x4 accB = {0.f, 0.f, 0.f, 0.f};
        #pragma unroll
        for (int c = 0; c < 4; ++c) {
            int byteA = buf * 8192 + ((l15 * 512 + (2 * c) * 64 + gq * 16) ^ ((l15 & 7) << 4));
            int byteB = buf * 8192 + ((l15 * 512 + (2 * c + 1) * 64 + gq * 16) ^ ((l15 & 7) << 4));
            const bf16x8 HA = *(const bf16x8*)(hbc + byteA);
            const bf16x8 HB = *(const bf16x8*)(hbc + byteB);
            accA = MFMA16(B2[2 * c], HA, accA);
            accB = MFMA16(B2[2 * c + 1], HB, accB);
        }
        float4 v;
        v.x = fmaxf(accA[0] + accB[0], 0.f); v.y = fmaxf(accA[1] + accB[1], 0.f);
        v.z = fmaxf(accA[2] + accB[2], 0.f); v.w = fmaxf(accA[3] + accB[3], 0.f);
        int r = m * 16 + l15;
        *(float4*)(phibuf + r * 132 + 16 * w + 4 * gq) = v;
        float sp = v.x * sav.x + v.y * sav.y + v.z * sav.z + v.w * sav.w;
        sp += __shfl_xor(sp, 16, 64);
        sp += __shfl_xor(sp, 32, 64);
        if (gq == 0) spart[w][r] = sp;
    };

    bf16x8 Xc[5];
    loadX(0, Xc);
    stage1(0, Xc);
    __syncthreads();
    #pragma unroll 1
    for (int m = 0; m < 5; ++m) {
        bf16x8 Xn[5];
        if (m < 4) loadX(m + 1, Xn);    // issue early, consume after stage2
        stage2(m, m & 1);
        if (m < 4) stage1((m + 1) & 1, Xn);
        __syncthreads();
    }

    // ---- softmax over 5 objects per batch ----
    if (tid < 16) {
        const float s0c = sab[0];
        float ss[5];
        #pragma unroll
        for (int o = 0; o < 5; ++o) {
            float s = s0c;
            #pragma unroll
            for (int ww = 0; ww < 8; ++ww) s += spart[ww][tid * 5 + o];
            ss[o] = s;
        }
        float mx = fmaxf(fmaxf(fmaxf(ss[0], ss[1]), fmaxf(ss[2], ss[3])), ss[4]);
        float ex[5]; float den = 0.f;
        #pragma unroll
        for (int o = 0; o < 5; ++o) { ex[o] = __expf(ss[o] - mx); den += ex[o]; }
        float inv = 1.0f / den;
        #pragma unroll
        for (int o = 0; o < 5; ++o) awb[tid * 5 + o] = ex[o] * inv;
    }
    __syncthreads();

    // ---- pooling: pooled[16][128] packed bf16 hi|lo ----
    #pragma unroll
    for (int rep = 0; rep < 4; ++rep) {
        int idx = rep * 512 + tid;       // < 2048
        int b = idx >> 7, c = idx & 127;
        float p = 0.f;
        #pragma unroll
        for (int o = 0; o < 5; ++o)
            p = fmaf(awb[b * 5 + o], phibuf[(b * 5 + o) * 132 + c], p);
        u16 hi = bf16_rne(p);
        u16 lo = bf16_lo(p, hi);
        poolw[b * 132 + c] = (u32)hi | ((u32)lo << 16);
    }
    __syncthreads();

    // ---- rho (swapped): A = pooled hi+lo, B = rhoW hi only ----
    {
        float4 rb0 = *(const float4*)(rhob + 16 * (2 * w + 0) + 4 * gq);
        float4 rb1 = *(const float4*)(rhob + 16 * (2 * w + 1) + 4 * gq);
        f32x4 acc0 = {rb0.x, rb0.y, rb0.z, rb0.w};
        f32x4 acc1 = {rb1.x, rb1.y, rb1.z, rb1.w};
        #pragma unroll
        for (int c = 0; c < 4; ++c) {
            uint4 q0 = *(const uint4*)(poolw + l15 * 132 + 32 * c + 8 * gq);
            uint4 q1 = *(const uint4*)(poolw + l15 * 132 + 32 * c + 8 * gq + 4);
            u32 ws[8] = {q0.x, q0.y, q0.z, q0.w, q1.x, q1.y, q1.z, q1.w};
            bf16x8 Ph, Pl;
            #pragma unroll
            for (int i = 0; i < 8; ++i) {
                Ph[i] = (short)(ws[i] & 0xffffu);
                Pl[i] = (short)(ws[i] >> 16);
            }
            #pragma unroll
            for (int t = 0; t < 2; ++t) {
                bf16x8 Bh = *(const bf16x8*)(BpR + (size_t)((c * 16 + 2 * w + t) * 2 + 0) * 512 + lane * 8);
                f32x4& a = t ? acc1 : acc0;
                a = MFMA16(Bh, Ph, a);
                a = MFMA16(Bh, Pl, a);
            }
        }
        #pragma unroll
        for (int t = 0; t < 2; ++t) {
            const f32x4& a = t ? acc1 : acc0;
            float4 v;
            v.x = fmaxf(a[0], 0.f); v.y = fmaxf(a[1], 0.f);
            v.z = fmaxf(a[2], 0.f); v.w = fmaxf(a[3], 0.f);
            *(float4*)(rbuf + l15 * 260 + 16 * (2 * w + t) + 4 * gq) = v;
        }
    }
    __syncthreads();

    // ---- heads: out[16][8] = r(16x256) @ headW(256x8) ----
    if (tid < 128) {
        int b = tid >> 3, q = tid & 7;
        float acc = 0.f;
        #pragma unroll 4
        for (int k = 0; k < 256; ++k)
            acc = fmaf(rbuf[b * 260 + k], headW[k * 8 + q], acc);
        int bg = blockIdx.x * 16 + b;
        if (q < 4) {
            outp[(size_t)bg * 4 + q] = acc + meanb[q];
        } else {
            float l = acc + lsb[q - 4];
            outp[65536 + (size_t)bg * 4 + (q - 4)] = fminf(fmaxf(l, -20.0f), 2.0f);
        }
    }
}

extern "C" void kernel_launch(void* const* d_in, const int* in_sizes, int n_in,
                              void* d_out, int out_size, void* d_ws, size_t ws_size,
                              hipStream_t stream)
{
    const float* obs   = (const float*)d_in[0];
    const float* ag    = (const float*)d_in[1];
    const float* g     = (const float*)d_in[2];
    const float* mpW1  = (const float*)d_in[3];
    const float* mpb1  = (const float*)d_in[4];
    const float* mpW2  = (const float*)d_in[5];
    const float* mpb2  = (const float*)d_in[6];
    const float* eaW   = (const float*)d_in[7];
    const float* eab   = (const float*)d_in[8];
    const float* phW1  = (const float*)d_in[9];
    const float* phb1  = (const float*)d_in[10];
    const float* phW2  = (const float*)d_in[11];
    const float* phb2  = (const float*)d_in[12];
    const float* saW   = (const float*)d_in[13];
    const float* sab   = (const float*)d_in[14];
    const float* rhoW  = (const float*)d_in[15];
    const float* rhob  = (const float*)d_in[16];
    const float* meanW = (const float*)d_in[17];
    const float* meanb = (const float*)d_in[18];
    const float* lsW   = (const float*)d_in[19];
    const float* lsb   = (const float*)d_in[20];
    const int*   src   = (const int*)d_in[21];
    const int*   dst   = (const int*)d_in[22];
    const int*   inc   = (const int*)d_in[23];
    const int*   pred  = (const int*)d_in[24];

    // workspace layout (bytes), total ~47.8 MB:
    //  Ein  (u16 327680x32) : [0, 20971520)
    //  Nin  (u16 81920x160) : [20971520, 47185920)
    //  Bp1e (u16 8192)      : [47185920, +16384)
    //  Bp2e (u16 65536)     : [47202304, +131072)
    //  BpC1 (u16 81920)     : [47333376, +163840)
    //  BpC2 (u16 65536)     : [47497216, +131072)
    //  BpR  (u16 65536)     : [47628288, +131072)
    char* ws = (char*)d_ws;
    u16* Ein  = (u16*)(ws + 0);
    u16* Nin  = (u16*)(ws + 20971520ull);
    u16* Bp1e = (u16*)(ws + 47185920ull);
    u16* Bp2e = (u16*)(ws + 47202304ull);
    u16* BpC1 = (u16*)(ws + 47333376ull);
    u16* BpC2 = (u16*)(ws + 47497216ull);
    u16* BpR  = (u16*)(ws + 47628288ull);

    hipLaunchKernelGGL(PREP, dim3(2720), dim3(256), 0, stream,
                       mpW1, mpW2, phW1, phW2, rhoW, Bp1e, Bp2e, BpC1, BpC2, BpR,
                       obs, ag, g, src, dst, pred, Ein, Nin);
    hipLaunchKernelGGL(GA, dim3(4096), dim3(512), 0, stream,
                       Ein, Bp1e, Bp2e, mpb1, mpb2, eaW, eab, inc, Nin);
    hipLaunchKernelGGL(GB, dim3(1024), dim3(512), 0, stream,
                       Nin, BpC1, BpC2, BpR, phb1, phb2, saW, sab, rhob,
                       meanW, meanb, lsW, lsb, (float*)d_out);
}